// Round 1
// baseline (1108.479 us; speedup 1.0000x reference)
//
#include <hip/hip_runtime.h>
#include <hip/hip_bf16.h>
#include <math.h>

#define NNODES 8192
#define NEDGES 131072
#define HID    512
#define NH     8
#define HC     64
#define UU     16
#define MM     512

// ---------------- feature build: x6[N][6] ----------------
__global__ __launch_bounds__(256) void k_build_x(
    const float* __restrict__ mc, const float* __restrict__ speeds,
    const float* __restrict__ dist, const float* __restrict__ ttg,
    const int* __restrict__ mask, float* __restrict__ x6)
{
    int n = blockIdx.x * blockDim.x + threadIdx.x;
    if (n >= NNODES) return;
    int u = n >> 9, m = n & 511;
    float* o = x6 + (size_t)n * 6;
    o[0] = mc[m * 2 + 0];
    o[1] = mc[m * 2 + 1];
    o[2] = (float)mask[u * MM + m];
    o[3] = speeds[u];
    o[4] = dist[u * MM + m];
    o[5] = ttg[u * MM + m];
}

// ---------------- layer-0 linear (in=6) ----------------
__global__ __launch_bounds__(256) void k_lin0(
    const float* __restrict__ x6, const float* __restrict__ W,
    const float* __restrict__ b, float* __restrict__ y)
{
    int i = blockIdx.x * blockDim.x + threadIdx.x; // n*512+j
    int n = i >> 9, j = i & 511;
    const float* xr = x6 + (size_t)n * 6;
    float s = b[j];
#pragma unroll
    for (int t = 0; t < 6; ++t) s += xr[t] * W[t * HID + j];
    y[i] = s;
}

// ---------------- fp32 tiled GEMM: Y[M,N] = X[M,K] @ W[K,N] + b ----------------
#define BM 64
#define BN 64
#define BK 16
__global__ __launch_bounds__(256) void k_gemm(
    const float* __restrict__ X, const float* __restrict__ W,
    const float* __restrict__ b, float* __restrict__ Y, int K, int N)
{
    __shared__ float As[BK][BM];
    __shared__ float Bs[BK][BN];
    int m0 = blockIdx.x * BM, n0 = blockIdx.y * BN;
    int t  = threadIdx.x;
    int tr = t >> 4, tc = t & 15;
    int ar = t >> 2;          // A row in tile  (0..63)
    int ac = (t & 3) * 4;     // A col (k)      {0,4,8,12}
    int br = t >> 4;          // B row (k)      (0..15)
    int bc = (t & 15) * 4;    // B col          (0..60)
    float acc[4][4] = {};
    for (int k0 = 0; k0 < K; k0 += BK) {
        float4 a4 = *(const float4*)(X + (size_t)(m0 + ar) * K + k0 + ac);
        As[ac + 0][ar] = a4.x; As[ac + 1][ar] = a4.y;
        As[ac + 2][ar] = a4.z; As[ac + 3][ar] = a4.w;
        *(float4*)&Bs[br][bc] = *(const float4*)(W + (size_t)(k0 + br) * N + n0 + bc);
        __syncthreads();
#pragma unroll
        for (int kk = 0; kk < BK; ++kk) {
            float a[4], bb[4];
#pragma unroll
            for (int i = 0; i < 4; ++i) a[i] = As[kk][tr * 4 + i];
#pragma unroll
            for (int j = 0; j < 4; ++j) bb[j] = Bs[kk][tc * 4 + j];
#pragma unroll
            for (int i = 0; i < 4; ++i)
#pragma unroll
                for (int j = 0; j < 4; ++j)
                    acc[i][j] += a[i] * bb[j];
        }
        __syncthreads();
    }
#pragma unroll
    for (int i = 0; i < 4; ++i) {
        int row = m0 + tr * 4 + i;
#pragma unroll
        for (int j = 0; j < 4; ++j) {
            int col = n0 + tc * 4 + j;
            Y[(size_t)row * N + col] = acc[i][j] + b[col];
        }
    }
}

// ---------------- CSR build ----------------
__global__ __launch_bounds__(256) void k_hist(const int* __restrict__ dst, int* __restrict__ cnt)
{
    int e = blockIdx.x * blockDim.x + threadIdx.x;
    if (e < NEDGES) atomicAdd(&cnt[dst[e]], 1);
}

__global__ __launch_bounds__(256) void k_scan(const int* __restrict__ cnt, int* __restrict__ indptr)
{
    __shared__ int sums[256];
    __shared__ int offs[256];
    int t = threadIdx.x;
    int base = t * 32;
    int s = 0;
    for (int i = 0; i < 32; ++i) s += cnt[base + i];
    sums[t] = s;
    __syncthreads();
    if (t == 0) {
        int run = 0;
        for (int i = 0; i < 256; ++i) { offs[i] = run; run += sums[i]; }
    }
    __syncthreads();
    int off = offs[t];
    for (int i = 0; i < 32; ++i) { indptr[base + i] = off; off += cnt[base + i]; }
    if (t == 255) indptr[NNODES] = off;
}

__global__ __launch_bounds__(256) void k_scatter(
    const int* __restrict__ src, const int* __restrict__ dst,
    const int* __restrict__ indptr, int* __restrict__ cursor, int* __restrict__ ssrc)
{
    int e = blockIdx.x * blockDim.x + threadIdx.x;
    if (e >= NEDGES) return;
    int d = dst[e];
    int p = atomicAdd(&cursor[d], 1);
    ssrc[indptr[d] + p] = src[e];
}

// ---------------- per-node attention aggregation (1 wave / node) ----------------
// lane l: head h = l>>3, 8-channel slice (l&7)*8; online softmax over incoming edges.
__global__ __launch_bounds__(64) void k_attn(
    const int* __restrict__ indptr, const int* __restrict__ ssrc,
    const float* __restrict__ q, const float* __restrict__ k,
    const float* __restrict__ v, float* __restrict__ xnext /* holds skip; overwritten */)
{
    int n = blockIdx.x;
    int l = threadIdx.x;
    int h = l >> 3, s8 = l & 7;
    int cbase = h * HC + s8 * 8;
    const float4* qp = (const float4*)(q + (size_t)n * HID + cbase);
    float4 q0 = qp[0], q1 = qp[1];
    float mrun = -INFINITY, ssum = 0.f;
    float acc[8] = {};
    int e0 = indptr[n], e1 = indptr[n + 1];
    for (int e = e0; e < e1; ++e) {
        int s = ssrc[e];
        const float4* kp = (const float4*)(k + (size_t)s * HID + cbase);
        float4 k0 = kp[0], k1 = kp[1];
        float part = q0.x * k0.x + q0.y * k0.y + q0.z * k0.z + q0.w * k0.w
                   + q1.x * k1.x + q1.y * k1.y + q1.z * k1.z + q1.w * k1.w;
        part += __shfl_xor(part, 1);
        part += __shfl_xor(part, 2);
        part += __shfl_xor(part, 4);
        float score = part * 0.125f;               // / sqrt(64)
        float mnew  = fmaxf(mrun, score);
        float sc    = __expf(mrun - mnew);
        float p     = __expf(score - mnew);
        ssum = ssum * sc + p;
        const float4* vp = (const float4*)(v + (size_t)s * HID + cbase);
        float4 v0 = vp[0], v1 = vp[1];
        acc[0] = acc[0] * sc + p * v0.x;  acc[1] = acc[1] * sc + p * v0.y;
        acc[2] = acc[2] * sc + p * v0.z;  acc[3] = acc[3] * sc + p * v0.w;
        acc[4] = acc[4] * sc + p * v1.x;  acc[5] = acc[5] * sc + p * v1.y;
        acc[6] = acc[6] * sc + p * v1.z;  acc[7] = acc[7] * sc + p * v1.w;
        mrun = mnew;
    }
    float inv = ssum > 0.f ? 1.f / ssum : 0.f;
    float* op = xnext + (size_t)n * HID + cbase;
#pragma unroll
    for (int j = 0; j < 8; ++j) {
        float y = op[j] + acc[j] * inv;
        op[j] = fmaxf(y, 0.f);                      // ReLU after every tconv layer
    }
}

// ---------------- pooling: xsum[u][c] = sum_m x[u*M+m][c] ----------------
__global__ __launch_bounds__(512) void k_pool(const float* __restrict__ x, float* __restrict__ xsum)
{
    int u = blockIdx.x;
    int c = threadIdx.x;
    const float* base = x + (size_t)u * MM * HID + c;
    float s = 0.f;
    for (int m = 0; m < MM; ++m) s += base[(size_t)m * HID];
    xsum[u * HID + c] = s;
}

// ---------------- uav_emb = xsum @ Wout + M*bout ----------------
__global__ __launch_bounds__(64) void k_emb(
    const float* __restrict__ xsum, const float* __restrict__ Wout,
    const float* __restrict__ bout, float* __restrict__ emb)
{
    int u = blockIdx.x, j = threadIdx.x;
    const float* xr = xsum + u * HID;
    float s = 0.f;
    for (int i = 0; i < HID; ++i) s += xr[i] * Wout[i * 64 + j];
    emb[u * 64 + j] = s + 512.0f * bout[j];
}

// ---------------- head: action_probs (==1) and state_values ----------------
__global__ __launch_bounds__(128) void k_head(
    const float* __restrict__ uavs, const float* __restrict__ speeds,
    const float* __restrict__ emb,
    const float* __restrict__ Wc1, const float* __restrict__ bc1,
    const float* __restrict__ Wc2, const float* __restrict__ bc2,
    float* __restrict__ out)
{
    __shared__ float comb[67];
    __shared__ float red[128];
    int u = blockIdx.x, t = threadIdx.x;
    if (t < 2) comb[t] = uavs[u * 2 + t];
    else if (t < 66) comb[t] = emb[u * 64 + (t - 2)];
    else if (t == 66) comb[t] = speeds[u];
    __syncthreads();
    float a = bc1[t];
    for (int i = 0; i < 67; ++i) a += comb[i] * Wc1[i * 128 + t];
    a = fmaxf(a, 0.f);
    red[t] = a * Wc2[t];
    __syncthreads();
    for (int sft = 64; sft > 0; sft >>= 1) {
        if (t < sft) red[t] += red[t + sft];
        __syncthreads();
    }
    if (t == 0) {
        out[u]      = 1.0f;               // softmax over a singleton axis
        out[16 + u] = red[0] + bc2[0];
    }
}

extern "C" void kernel_launch(void* const* d_in, const int* in_sizes, int n_in,
                              void* d_out, int out_size, void* d_ws, size_t ws_size,
                              hipStream_t stream)
{
    // ---- inputs ----
    const float* mission_coords = (const float*)d_in[0];
    const float* uavs_info      = (const float*)d_in[1];
    const float* speeds         = (const float*)d_in[2];
    const float* dist_matrix    = (const float*)d_in[3];
    const float* timetogo       = (const float*)d_in[4];
    const int*   action_mask    = (const int*)d_in[5];
    const int*   edge_index     = (const int*)d_in[6];
    const float* Wq0 = (const float*)d_in[8];  const float* bq0 = (const float*)d_in[9];
    const float* Wk0 = (const float*)d_in[10]; const float* bk0 = (const float*)d_in[11];
    const float* Wv0 = (const float*)d_in[12]; const float* bv0 = (const float*)d_in[13];
    const float* Ws0 = (const float*)d_in[14]; const float* bs0 = (const float*)d_in[15];
    const float* Wq  = (const float*)d_in[16]; const float* bq  = (const float*)d_in[17];
    const float* Wk  = (const float*)d_in[18]; const float* bk  = (const float*)d_in[19];
    const float* Wv  = (const float*)d_in[20]; const float* bv  = (const float*)d_in[21];
    const float* Ws  = (const float*)d_in[22]; const float* bs  = (const float*)d_in[23];
    const float* Wout = (const float*)d_in[24]; const float* bout = (const float*)d_in[25];
    const float* Wc1 = (const float*)d_in[30]; const float* bc1 = (const float*)d_in[31];
    const float* Wc2 = (const float*)d_in[32]; const float* bc2 = (const float*)d_in[33];
    float* out = (float*)d_out;

    const int* e_src = edge_index;
    const int* e_dst = edge_index + NEDGES;

    // ---- workspace layout ----
    float* f    = (float*)d_ws;
    float* x6   = f;                       // 49152
    float* xA   = x6 + 49152;              // 4194304
    float* xB   = xA + 4194304;
    float* q    = xB + 4194304;
    float* kk   = q  + 4194304;
    float* vv   = kk + 4194304;
    float* xsum = vv + 4194304;            // 8192
    float* emb  = xsum + 8192;             // 1024
    int* cnt    = (int*)(emb + 1024);
    int* indptr = cnt + NNODES;
    int* cursor = indptr + NNODES + 1;
    int* ssrc   = cursor + NNODES;

    hipMemsetAsync(cnt, 0, NNODES * sizeof(int), stream);
    hipMemsetAsync(cursor, 0, NNODES * sizeof(int), stream);

    // ---- graph CSR + features ----
    k_build_x<<<NNODES / 256, 256, 0, stream>>>(mission_coords, speeds, dist_matrix,
                                                timetogo, action_mask, x6);
    k_hist<<<NEDGES / 256, 256, 0, stream>>>(e_dst, cnt);
    k_scan<<<1, 256, 0, stream>>>(cnt, indptr);
    k_scatter<<<NEDGES / 256, 256, 0, stream>>>(e_src, e_dst, indptr, cursor, ssrc);

    const int linblocks = NNODES * HID / 256;

    // ---- layer 0 (in=6) ----
    k_lin0<<<linblocks, 256, 0, stream>>>(x6, Wq0, bq0, q);
    k_lin0<<<linblocks, 256, 0, stream>>>(x6, Wk0, bk0, kk);
    k_lin0<<<linblocks, 256, 0, stream>>>(x6, Wv0, bv0, vv);
    k_lin0<<<linblocks, 256, 0, stream>>>(x6, Ws0, bs0, xA);
    k_attn<<<NNODES, 64, 0, stream>>>(indptr, ssrc, q, kk, vv, xA);

    // ---- layers 1..3 ----
    float* cur = xA;
    float* nxt = xB;
    dim3 ggrid(NNODES / BM, HID / BN);
    for (int l = 0; l < 3; ++l) {
        const float* wq = Wq + (size_t)l * HID * HID; const float* bql = bq + l * HID;
        const float* wk = Wk + (size_t)l * HID * HID; const float* bkl = bk + l * HID;
        const float* wv = Wv + (size_t)l * HID * HID; const float* bvl = bv + l * HID;
        const float* ws = Ws + (size_t)l * HID * HID; const float* bsl = bs + l * HID;
        k_gemm<<<ggrid, 256, 0, stream>>>(cur, wq, bql, q,  HID, HID);
        k_gemm<<<ggrid, 256, 0, stream>>>(cur, wk, bkl, kk, HID, HID);
        k_gemm<<<ggrid, 256, 0, stream>>>(cur, wv, bvl, vv, HID, HID);
        k_gemm<<<ggrid, 256, 0, stream>>>(cur, ws, bsl, nxt, HID, HID);
        k_attn<<<NNODES, 64, 0, stream>>>(indptr, ssrc, q, kk, vv, nxt);
        float* tmp = cur; cur = nxt; nxt = tmp;
    }

    // ---- pooling + embedding + head ----
    k_pool<<<UU, 512, 0, stream>>>(cur, xsum);
    k_emb<<<UU, 64, 0, stream>>>(xsum, Wout, bout, emb);
    k_head<<<UU, 128, 0, stream>>>(uavs_info, speeds, emb, Wc1, bc1, Wc2, bc2, out);
}

// Round 2
// 394.863 us; speedup vs baseline: 2.8073x; 2.8073x over previous
//
#include <hip/hip_runtime.h>
#include <hip/hip_bf16.h>
#include <math.h>

#define NNODES 8192
#define NEDGES 131072
#define HID    512
#define UU     16
#define MM     512
#define NQKVS  2048   // packed q|k|v|s columns

typedef __attribute__((ext_vector_type(8))) short bf16x8;
typedef __attribute__((ext_vector_type(4))) float f32x4;

__device__ __forceinline__ float bf2f(ushort u) {
    return __uint_as_float(((unsigned)u) << 16);
}
__device__ __forceinline__ ushort f2bf(float f) {
    unsigned x = __float_as_uint(f);
    return (ushort)((x + 0x7fffu + ((x >> 16) & 1u)) >> 16);
}

// ---------------- feature build: x6[N][6] ----------------
__global__ __launch_bounds__(256) void k_build_x(
    const float* __restrict__ mc, const float* __restrict__ speeds,
    const float* __restrict__ dist, const float* __restrict__ ttg,
    const int* __restrict__ mask, float* __restrict__ x6)
{
    int n = blockIdx.x * blockDim.x + threadIdx.x;
    if (n >= NNODES) return;
    int u = n >> 9, m = n & 511;
    float* o = x6 + (size_t)n * 6;
    o[0] = mc[m * 2 + 0];
    o[1] = mc[m * 2 + 1];
    o[2] = (float)mask[u * MM + m];
    o[3] = speeds[u];
    o[4] = dist[u * MM + m];
    o[5] = ttg[u * MM + m];
}

// ---------------- weight transpose+convert: Wt[l][2048][512] bf16 ----------------
__global__ __launch_bounds__(256) void k_wt(
    const float* __restrict__ Wq, const float* __restrict__ Wk,
    const float* __restrict__ Wv, const float* __restrict__ Ws,
    ushort* __restrict__ Wt)
{
    __shared__ float tile[64][65];
    int z = blockIdx.z;                 // 12 matrices: l*4+which
    int l = z >> 2, which = z & 3;
    const float* src = (which == 0 ? Wq : which == 1 ? Wk : which == 2 ? Wv : Ws)
                       + (size_t)l * HID * HID;
    int k0 = blockIdx.x * 64, c0 = blockIdx.y * 64;
    int t = threadIdx.x;
#pragma unroll
    for (int i = 0; i < 16; ++i) {
        int idx = i * 256 + t;
        if (idx >= 4096) break;
    }
#pragma unroll
    for (int i = 0; i < 16; ++i) {
        int idx = i * 256 + t;
        int r = idx >> 6, c = idx & 63;
        tile[r][c] = src[(size_t)(k0 + r) * HID + c0 + c];
    }
    __syncthreads();
    ushort* dst = Wt + ((size_t)l * NQKVS + which * HID + c0) * HID + k0;
#pragma unroll
    for (int i = 0; i < 16; ++i) {
        int idx = i * 256 + t;
        int r = idx >> 6, c = idx & 63;
        dst[(size_t)r * HID + c] = f2bf(tile[c][r]);
    }
}

// ---------------- bias pack: bcat[3][2048] ----------------
__global__ __launch_bounds__(256) void k_bias(
    const float* __restrict__ bq, const float* __restrict__ bk,
    const float* __restrict__ bv, const float* __restrict__ bs,
    float* __restrict__ bcat)
{
    int i = blockIdx.x * 256 + threadIdx.x;   // [3][2048]
    int l = i >> 11, j = i & 2047;
    int which = j >> 9, jj = j & 511;
    const float* b = which == 0 ? bq : which == 1 ? bk : which == 2 ? bv : bs;
    bcat[i] = b[l * HID + jj];
}

// ---------------- layer-0 linear (in=6) -> packed Y bf16 ----------------
__global__ __launch_bounds__(256) void k_lin0(
    const float* __restrict__ x6,
    const float* __restrict__ Wq0, const float* __restrict__ bq0,
    const float* __restrict__ Wk0, const float* __restrict__ bk0,
    const float* __restrict__ Wv0, const float* __restrict__ bv0,
    const float* __restrict__ Ws0, const float* __restrict__ bs0,
    ushort* __restrict__ Y)
{
    int gid = blockIdx.x * 256 + threadIdx.x;  // n*2048 + j
    int n = gid >> 11, j = gid & 2047;
    int which = j >> 9, jj = j & 511;
    const float* W = which == 0 ? Wq0 : which == 1 ? Wk0 : which == 2 ? Wv0 : Ws0;
    const float* b = which == 0 ? bq0 : which == 1 ? bk0 : which == 2 ? bv0 : bs0;
    const float* xr = x6 + (size_t)n * 6;
    float s = b[jj];
#pragma unroll
    for (int tt = 0; tt < 6; ++tt) s = fmaf(xr[tt], W[tt * HID + jj], s);
    Y[gid] = f2bf(s);
}

// ---------------- bf16 MFMA GEMM: Y[8192][2048] = X[8192][512] @ Wt^T + bias ----------------
// 128x128 tile, BK=32, 4 waves (2x2), each wave 64x64 via 4x4 frags of 16x16x32.
// LDS per matrix-tile: 4 kq-chunks of 128x16B with 32B skew between chunks (bank spread).
#define GBM 128
#define GBN 128
#define GBK 32
#define CH_SKEW 2080
#define TILEB (4 * CH_SKEW)

__device__ __forceinline__ void stage_pair(
    const ushort* __restrict__ Ag, const ushort* __restrict__ Bg,
    char* la, char* lb, int t)
{
#pragma unroll
    for (int c = 0; c < 2; ++c) {
        int idx = c * 256 + t;
        int kq = idx >> 7, row = idx & 127;
        __builtin_amdgcn_global_load_lds(
            (const __attribute__((address_space(1))) void*)(Ag + (size_t)row * HID + kq * 8),
            (__attribute__((address_space(3))) void*)(la + kq * CH_SKEW + row * 16), 16, 0, 0);
        __builtin_amdgcn_global_load_lds(
            (const __attribute__((address_space(1))) void*)(Bg + (size_t)row * HID + kq * 8),
            (__attribute__((address_space(3))) void*)(lb + kq * CH_SKEW + row * 16), 16, 0, 0);
    }
}

__global__ __launch_bounds__(256) void k_gemm(
    const ushort* __restrict__ A,    // [8192][512] bf16
    const ushort* __restrict__ Bt,   // [2048][512] bf16 (weights, col-major i.e. [n][k])
    const float* __restrict__ bias,  // [2048] fp32
    ushort* __restrict__ Y)          // [8192][2048] bf16
{
    __shared__ char lds[4 * TILEB];  // [2 buf][A,B]
    const int t = threadIdx.x;
    const int m0 = blockIdx.x * GBM, n0 = blockIdx.y * GBN;
    const int wid = t >> 6, lane = t & 63;
    const int wr = wid >> 1, wc = wid & 1;
    const int l15 = lane & 15, lkq = lane >> 4;

    f32x4 acc[4][4] = {};

    const int aoff = lkq * CH_SKEW + (wr * 64 + l15) * 16;
    const int boff = lkq * CH_SKEW + (wc * 64 + l15) * 16;

    stage_pair(A + (size_t)m0 * HID, Bt + (size_t)n0 * HID,
               lds, lds + TILEB, t);
    int cur = 0;
    const int NKS = HID / GBK;   // 16
    for (int ks = 0; ks < NKS; ++ks) {
        __syncthreads();   // drains vmcnt (staged buf[cur]) + lgkmcnt
        if (ks + 1 < NKS) {
            int k0 = (ks + 1) * GBK;
            stage_pair(A + (size_t)m0 * HID + k0, Bt + (size_t)n0 * HID + k0,
                       lds + (cur ^ 1) * 2 * TILEB, lds + (cur ^ 1) * 2 * TILEB + TILEB, t);
        }
        const char* la = lds + cur * 2 * TILEB;
        const char* lb = la + TILEB;
        bf16x8 a[4], b[4];
#pragma unroll
        for (int i = 0; i < 4; ++i) a[i] = *(const bf16x8*)(la + aoff + i * 256);
#pragma unroll
        for (int j = 0; j < 4; ++j) b[j] = *(const bf16x8*)(lb + boff + j * 256);
#pragma unroll
        for (int i = 0; i < 4; ++i)
#pragma unroll
            for (int j = 0; j < 4; ++j)
                acc[i][j] = __builtin_amdgcn_mfma_f32_16x16x32_bf16(a[i], b[j], acc[i][j], 0, 0, 0);
        cur ^= 1;
    }

    // epilogue: C/D layout col=lane&15, row=(lane>>4)*4+reg
#pragma unroll
    for (int i = 0; i < 4; ++i) {
        int row = m0 + wr * 64 + i * 16 + lkq * 4;
#pragma unroll
        for (int j = 0; j < 4; ++j) {
            int col = n0 + wc * 64 + j * 16 + l15;
            float bc = bias[col];
            f32x4 r = acc[i][j];
#pragma unroll
            for (int g = 0; g < 4; ++g)
                Y[(size_t)(row + g) * NQKVS + col] = f2bf(r[g] + bc);
        }
    }
}

// ---------------- CSR build ----------------
__global__ __launch_bounds__(256) void k_hist(const int* __restrict__ dst, int* __restrict__ cnt)
{
    int e = blockIdx.x * blockDim.x + threadIdx.x;
    if (e < NEDGES) atomicAdd(&cnt[dst[e]], 1);
}

__global__ __launch_bounds__(256) void k_scan(const int* __restrict__ cnt, int* __restrict__ indptr)
{
    __shared__ int sums[256];
    __shared__ int offs[256];
    int t = threadIdx.x;
    int base = t * 32;
    int s = 0;
    for (int i = 0; i < 32; ++i) s += cnt[base + i];
    sums[t] = s;
    __syncthreads();
    if (t == 0) {
        int run = 0;
        for (int i = 0; i < 256; ++i) { offs[i] = run; run += sums[i]; }
    }
    __syncthreads();
    int off = offs[t];
    for (int i = 0; i < 32; ++i) { indptr[base + i] = off; off += cnt[base + i]; }
    if (t == 255) indptr[NNODES] = off;
}

__global__ __launch_bounds__(256) void k_scatter(
    const int* __restrict__ src, const int* __restrict__ dst,
    const int* __restrict__ indptr, int* __restrict__ cursor, int* __restrict__ ssrc)
{
    int e = blockIdx.x * blockDim.x + threadIdx.x;
    if (e >= NEDGES) return;
    int d = dst[e];
    int p = atomicAdd(&cursor[d], 1);
    ssrc[indptr[d] + p] = src[e];
}

// ---------------- per-node attention (1 wave/node), bf16, 1-edge prefetch ----------------
// lane l handles channels [l*8, l*8+8); heads are 8-lane groups (shfl_xor 1,2,4).
__global__ __launch_bounds__(64) void k_attn(
    const int* __restrict__ indptr, const int* __restrict__ ssrc,
    const ushort* __restrict__ Y,   // [N][2048] packed q|k|v|s
    ushort* __restrict__ X)         // [N][512] bf16 out
{
    int n = blockIdx.x;
    int l = threadIdx.x;
    int cbase = l * 8;
    const ushort* yq = Y + (size_t)n * NQKVS + cbase;
    float qf[8];
    {
        bf16x8 q8 = *(const bf16x8*)yq;
#pragma unroll
        for (int j = 0; j < 8; ++j) qf[j] = bf2f((ushort)q8[j]);
    }
    float mrun = -INFINITY, ssum = 0.f;
    float acc[8] = {};
    int e0 = indptr[n], e1 = indptr[n + 1];
    bf16x8 kN = {}, vN = {};
    if (e0 < e1) {
        int s = ssrc[e0];
        const ushort* yr = Y + (size_t)s * NQKVS + cbase;
        kN = *(const bf16x8*)(yr + 512);
        vN = *(const bf16x8*)(yr + 1024);
    }
    for (int e = e0; e < e1; ++e) {
        bf16x8 k8 = kN, v8 = vN;
        if (e + 1 < e1) {
            int s = ssrc[e + 1];
            const ushort* yr = Y + (size_t)s * NQKVS + cbase;
            kN = *(const bf16x8*)(yr + 512);
            vN = *(const bf16x8*)(yr + 1024);
        }
        float part = 0.f;
#pragma unroll
        for (int j = 0; j < 8; ++j) part = fmaf(qf[j], bf2f((ushort)k8[j]), part);
        part += __shfl_xor(part, 1);
        part += __shfl_xor(part, 2);
        part += __shfl_xor(part, 4);
        float score = part * 0.125f;            // / sqrt(64)
        float mnew = fmaxf(mrun, score);
        float sc = __expf(mrun - mnew);
        float p = __expf(score - mnew);
        ssum = ssum * sc + p;
#pragma unroll
        for (int j = 0; j < 8; ++j)
            acc[j] = fmaf(acc[j], sc, p * bf2f((ushort)v8[j]));
        mrun = mnew;
    }
    float inv = ssum > 0.f ? 1.f / ssum : 0.f;
    bf16x8 o8;
#pragma unroll
    for (int j = 0; j < 8; ++j) {
        float o = fmaxf(fmaf(acc[j], inv, bf2f(yq[1536 + j])), 0.f);  // + skip, ReLU
        o8[j] = (short)f2bf(o);
    }
    *(bf16x8*)(X + (size_t)n * HID + cbase) = o8;
}

// ---------------- pooling: xsum[u][c] = sum_m X[u*M+m][c] ----------------
__global__ __launch_bounds__(512) void k_pool(const ushort* __restrict__ X, float* __restrict__ xsum)
{
    int u = blockIdx.x;
    int c = threadIdx.x;
    const ushort* base = X + (size_t)u * MM * HID + c;
    float s = 0.f;
    for (int m = 0; m < MM; ++m) s += bf2f(base[(size_t)m * HID]);
    xsum[u * HID + c] = s;
}

// ---------------- uav_emb = xsum @ Wout + M*bout ----------------
__global__ __launch_bounds__(64) void k_emb(
    const float* __restrict__ xsum, const float* __restrict__ Wout,
    const float* __restrict__ bout, float* __restrict__ emb)
{
    int u = blockIdx.x, j = threadIdx.x;
    const float* xr = xsum + u * HID;
    float s = 0.f;
    for (int i = 0; i < HID; ++i) s = fmaf(xr[i], Wout[i * 64 + j], s);
    emb[u * 64 + j] = s + 512.0f * bout[j];
}

// ---------------- head ----------------
__global__ __launch_bounds__(128) void k_head(
    const float* __restrict__ uavs, const float* __restrict__ speeds,
    const float* __restrict__ emb,
    const float* __restrict__ Wc1, const float* __restrict__ bc1,
    const float* __restrict__ Wc2, const float* __restrict__ bc2,
    float* __restrict__ out)
{
    __shared__ float comb[67];
    __shared__ float red[128];
    int u = blockIdx.x, t = threadIdx.x;
    if (t < 2) comb[t] = uavs[u * 2 + t];
    else if (t < 66) comb[t] = emb[u * 64 + (t - 2)];
    else if (t == 66) comb[t] = speeds[u];
    __syncthreads();
    float a = bc1[t];
    for (int i = 0; i < 67; ++i) a = fmaf(comb[i], Wc1[i * 128 + t], a);
    a = fmaxf(a, 0.f);
    red[t] = a * Wc2[t];
    __syncthreads();
    for (int sft = 64; sft > 0; sft >>= 1) {
        if (t < sft) red[t] += red[t + sft];
        __syncthreads();
    }
    if (t == 0) {
        out[u]      = 1.0f;                 // softmax over singleton axis
        out[16 + u] = red[0] + bc2[0];
    }
}

extern "C" void kernel_launch(void* const* d_in, const int* in_sizes, int n_in,
                              void* d_out, int out_size, void* d_ws, size_t ws_size,
                              hipStream_t stream)
{
    const float* mission_coords = (const float*)d_in[0];
    const float* uavs_info      = (const float*)d_in[1];
    const float* speeds         = (const float*)d_in[2];
    const float* dist_matrix    = (const float*)d_in[3];
    const float* timetogo       = (const float*)d_in[4];
    const int*   action_mask    = (const int*)d_in[5];
    const int*   edge_index     = (const int*)d_in[6];
    const float* Wq0 = (const float*)d_in[8];  const float* bq0 = (const float*)d_in[9];
    const float* Wk0 = (const float*)d_in[10]; const float* bk0 = (const float*)d_in[11];
    const float* Wv0 = (const float*)d_in[12]; const float* bv0 = (const float*)d_in[13];
    const float* Ws0 = (const float*)d_in[14]; const float* bs0 = (const float*)d_in[15];
    const float* Wq  = (const float*)d_in[16]; const float* bq  = (const float*)d_in[17];
    const float* Wk  = (const float*)d_in[18]; const float* bk  = (const float*)d_in[19];
    const float* Wv  = (const float*)d_in[20]; const float* bv  = (const float*)d_in[21];
    const float* Ws  = (const float*)d_in[22]; const float* bs  = (const float*)d_in[23];
    const float* Wout = (const float*)d_in[24]; const float* bout = (const float*)d_in[25];
    const float* Wc1 = (const float*)d_in[30]; const float* bc1 = (const float*)d_in[31];
    const float* Wc2 = (const float*)d_in[32]; const float* bc2 = (const float*)d_in[33];
    float* out = (float*)d_out;

    const int* e_src = edge_index;
    const int* e_dst = edge_index + NEDGES;

    // ---- workspace carve ----
    char* p = (char*)d_ws;
    ushort* Ybf = (ushort*)p;  p += (size_t)NNODES * NQKVS * 2;   // 32 MB
    ushort* Xbf = (ushort*)p;  p += (size_t)NNODES * HID * 2;     // 8 MB
    ushort* Wt  = (ushort*)p;  p += (size_t)3 * NQKVS * HID * 2;  // 6 MB
    float* bcat = (float*)p;   p += (size_t)3 * NQKVS * 4;
    float* x6   = (float*)p;   p += (size_t)NNODES * 6 * 4;
    float* xsum = (float*)p;   p += (size_t)UU * HID * 4;
    float* emb  = (float*)p;   p += (size_t)UU * 64 * 4;
    int* cnt    = (int*)p;     p += (size_t)NNODES * 4;
    int* indptr = (int*)p;     p += (size_t)(NNODES + 1) * 4;
    int* cursor = (int*)p;     p += (size_t)NNODES * 4;
    int* ssrc   = (int*)p;     p += (size_t)NEDGES * 4;

    hipMemsetAsync(cnt, 0, NNODES * sizeof(int), stream);
    hipMemsetAsync(cursor, 0, NNODES * sizeof(int), stream);

    // ---- prep: features, weights, CSR ----
    k_build_x<<<NNODES / 256, 256, 0, stream>>>(mission_coords, speeds, dist_matrix,
                                                timetogo, action_mask, x6);
    k_wt<<<dim3(8, 8, 12), 256, 0, stream>>>(Wq, Wk, Wv, Ws, Wt);
    k_bias<<<3 * NQKVS / 256, 256, 0, stream>>>(bq, bk, bv, bs, bcat);
    k_hist<<<NEDGES / 256, 256, 0, stream>>>(e_dst, cnt);
    k_scan<<<1, 256, 0, stream>>>(cnt, indptr);
    k_scatter<<<NEDGES / 256, 256, 0, stream>>>(e_src, e_dst, indptr, cursor, ssrc);

    // ---- layer 0 (in=6) ----
    k_lin0<<<(size_t)NNODES * NQKVS / 256, 256, 0, stream>>>(
        x6, Wq0, bq0, Wk0, bk0, Wv0, bv0, Ws0, bs0, Ybf);
    k_attn<<<NNODES, 64, 0, stream>>>(indptr, ssrc, Ybf, Xbf);

    // ---- layers 1..3: fused q|k|v|s MFMA GEMM + attention ----
    dim3 ggrid(NNODES / GBM, NQKVS / GBN);   // 64 x 16
    for (int l = 0; l < 3; ++l) {
        k_gemm<<<ggrid, 256, 0, stream>>>(Xbf, Wt + (size_t)l * NQKVS * HID,
                                          bcat + l * NQKVS, Ybf);
        k_attn<<<NNODES, 64, 0, stream>>>(indptr, ssrc, Ybf, Xbf);
    }

    // ---- pooling + embedding + head ----
    k_pool<<<UU, 512, 0, stream>>>(Xbf, xsum);
    k_emb<<<UU, 64, 0, stream>>>(xsum, Wout, bout, emb);
    k_head<<<UU, 128, 0, stream>>>(uavs_info, speeds, emb, Wc1, bc1, Wc2, bc2, out);
}

// Round 3
// 384.157 us; speedup vs baseline: 2.8855x; 1.0279x over previous
//
#include <hip/hip_runtime.h>
#include <hip/hip_bf16.h>
#include <math.h>

#define NNODES 8192
#define NEDGES 131072
#define HID    512
#define UU     16
#define MM     512
#define NQKVS  2048   // packed q|k|v|s columns

typedef __attribute__((ext_vector_type(8))) short bf16x8;
typedef __attribute__((ext_vector_type(4))) float f32x4;

__device__ __forceinline__ float bf2f(ushort u) {
    return __uint_as_float(((unsigned)u) << 16);
}
__device__ __forceinline__ ushort f2bf(float f) {
    unsigned x = __float_as_uint(f);
    return (ushort)((x + 0x7fffu + ((x >> 16) & 1u)) >> 16);
}

// ---------------- feature build: x6[N][6] ----------------
__global__ __launch_bounds__(256) void k_build_x(
    const float* __restrict__ mc, const float* __restrict__ speeds,
    const float* __restrict__ dist, const float* __restrict__ ttg,
    const int* __restrict__ mask, float* __restrict__ x6)
{
    int n = blockIdx.x * blockDim.x + threadIdx.x;
    if (n >= NNODES) return;
    int u = n >> 9, m = n & 511;
    float* o = x6 + (size_t)n * 6;
    o[0] = mc[m * 2 + 0];
    o[1] = mc[m * 2 + 1];
    o[2] = (float)mask[u * MM + m];
    o[3] = speeds[u];
    o[4] = dist[u * MM + m];
    o[5] = ttg[u * MM + m];
}

// ---------------- weight transpose+convert: Wt[l][2048][512] bf16 ----------------
__global__ __launch_bounds__(256) void k_wt(
    const float* __restrict__ Wq, const float* __restrict__ Wk,
    const float* __restrict__ Wv, const float* __restrict__ Ws,
    ushort* __restrict__ Wt)
{
    __shared__ float tile[64][65];
    int z = blockIdx.z;                 // 12 matrices: l*4+which
    int l = z >> 2, which = z & 3;
    const float* src = (which == 0 ? Wq : which == 1 ? Wk : which == 2 ? Wv : Ws)
                       + (size_t)l * HID * HID;
    int k0 = blockIdx.x * 64, c0 = blockIdx.y * 64;
    int t = threadIdx.x;
#pragma unroll
    for (int i = 0; i < 16; ++i) {
        int idx = i * 256 + t;
        int r = idx >> 6, c = idx & 63;
        tile[r][c] = src[(size_t)(k0 + r) * HID + c0 + c];
    }
    __syncthreads();
    ushort* dst = Wt + ((size_t)l * NQKVS + which * HID + c0) * HID + k0;
#pragma unroll
    for (int i = 0; i < 16; ++i) {
        int idx = i * 256 + t;
        int r = idx >> 6, c = idx & 63;
        dst[(size_t)r * HID + c] = f2bf(tile[c][r]);
    }
}

// ---------------- bias pack: bcat[3][2048] ----------------
__global__ __launch_bounds__(256) void k_bias(
    const float* __restrict__ bq, const float* __restrict__ bk,
    const float* __restrict__ bv, const float* __restrict__ bs,
    float* __restrict__ bcat)
{
    int i = blockIdx.x * 256 + threadIdx.x;   // [3][2048]
    int l = i >> 11, j = i & 2047;
    int which = j >> 9, jj = j & 511;
    const float* b = which == 0 ? bq : which == 1 ? bk : which == 2 ? bv : bs;
    bcat[i] = b[l * HID + jj];
}

// ---------------- layer-0 linear (in=6) -> packed Y bf16 ----------------
__global__ __launch_bounds__(256) void k_lin0(
    const float* __restrict__ x6,
    const float* __restrict__ Wq0, const float* __restrict__ bq0,
    const float* __restrict__ Wk0, const float* __restrict__ bk0,
    const float* __restrict__ Wv0, const float* __restrict__ bv0,
    const float* __restrict__ Ws0, const float* __restrict__ bs0,
    ushort* __restrict__ Y)
{
    int gid = blockIdx.x * 256 + threadIdx.x;  // n*2048 + j
    int n = gid >> 11, j = gid & 2047;
    int which = j >> 9, jj = j & 511;
    const float* W = which == 0 ? Wq0 : which == 1 ? Wk0 : which == 2 ? Wv0 : Ws0;
    const float* b = which == 0 ? bq0 : which == 1 ? bk0 : which == 2 ? bv0 : bs0;
    const float* xr = x6 + (size_t)n * 6;
    float s = b[jj];
#pragma unroll
    for (int tt = 0; tt < 6; ++tt) s = fmaf(xr[tt], W[tt * HID + jj], s);
    Y[gid] = f2bf(s);
}

// ---------------- bf16 MFMA GEMM: Y[8192][2048] = X[8192][512] @ Wt^T + bias ----------------
// 256x256 tile, BK=64, 8 waves (2M x 4N), each wave 128x64 via 8x4 frags of 16x16x32.
// LDS per matrix-tile: 8 kq-chunks of 256 rows x 16B, stride 4128 (32B skew).
// 2-phase double-buffered: stage(next) -> compute(cur) -> __syncthreads.
#define GBM 256
#define GBN 256
#define GBK 64
#define CH_STRIDE 4128          // 256*16 + 32 skew
#define MATB (8 * CH_STRIDE)    // 33024 per matrix
#define BUFB (2 * MATB)         // 66048 per buffer (A+B)

__device__ __forceinline__ void stage_tile(
    const ushort* __restrict__ Ag, const ushort* __restrict__ Bg,
    char* __restrict__ la, char* __restrict__ lb, int t)
{
    const int w = t >> 6, l = t & 63;
    const int row = ((w & 3) << 6) + l;         // 0..255
    const int kq0 = (w >> 2);                   // 0 or 1
#pragma unroll
    for (int p = 0; p < 4; ++p) {
        int kq = p * 2 + kq0;
        __builtin_amdgcn_global_load_lds(
            (const __attribute__((address_space(1))) void*)(Ag + (size_t)row * HID + kq * 8),
            (__attribute__((address_space(3))) void*)(la + kq * CH_STRIDE + row * 16), 16, 0, 0);
        __builtin_amdgcn_global_load_lds(
            (const __attribute__((address_space(1))) void*)(Bg + (size_t)row * HID + kq * 8),
            (__attribute__((address_space(3))) void*)(lb + kq * CH_STRIDE + row * 16), 16, 0, 0);
    }
}

__global__ __launch_bounds__(512, 2) void k_gemm(
    const ushort* __restrict__ A,    // [8192][512] bf16
    const ushort* __restrict__ Bt,   // [2048][512] bf16 (weights, [n][k])
    const float* __restrict__ bias,  // [2048] fp32
    ushort* __restrict__ Y)          // [8192][2048] bf16
{
    __shared__ char lds[2 * BUFB];   // 132096 B
    const int t = threadIdx.x;
    const int m0 = blockIdx.x * GBM, n0 = blockIdx.y * GBN;
    const int wid = t >> 6, lane = t & 63;
    const int wr = wid >> 2, wc = wid & 3;      // 2M x 4N
    const int l15 = lane & 15, lkq = lane >> 4;

    f32x4 acc[8][4] = {};

    const ushort* Ab = A + (size_t)m0 * HID;
    const ushort* Bb = Bt + (size_t)n0 * HID;

    stage_tile(Ab, Bb, lds, lds + MATB, t);
    int cur = 0;
    const int NKS = HID / GBK;   // 8
    for (int ks = 0; ks < NKS; ++ks) {
        __syncthreads();   // drains vmcnt (stage of buf[cur]) + prior reads of buf[cur^1]
        if (ks + 1 < NKS) {
            int k0 = (ks + 1) * GBK;
            stage_tile(Ab + k0, Bb + k0,
                       lds + (cur ^ 1) * BUFB, lds + (cur ^ 1) * BUFB + MATB, t);
        }
        const char* la = lds + cur * BUFB;
        const char* lb = la + MATB;
#pragma unroll
        for (int kh = 0; kh < 2; ++kh) {
            const int cb = (kh * 4 + lkq) * CH_STRIDE;
            bf16x8 a[8], b[4];
#pragma unroll
            for (int i = 0; i < 8; ++i)
                a[i] = *(const bf16x8*)(la + cb + (wr * 128 + i * 16 + l15) * 16);
#pragma unroll
            for (int j = 0; j < 4; ++j)
                b[j] = *(const bf16x8*)(lb + cb + (wc * 64 + j * 16 + l15) * 16);
#pragma unroll
            for (int i = 0; i < 8; ++i)
#pragma unroll
                for (int j = 0; j < 4; ++j)
                    acc[i][j] = __builtin_amdgcn_mfma_f32_16x16x32_bf16(a[i], b[j], acc[i][j], 0, 0, 0);
        }
        cur ^= 1;
    }

    // epilogue: C/D layout col=lane&15, row=(lane>>4)*4+reg
#pragma unroll
    for (int i = 0; i < 8; ++i) {
        int row = m0 + wr * 128 + i * 16 + lkq * 4;
#pragma unroll
        for (int j = 0; j < 4; ++j) {
            int col = n0 + wc * 64 + j * 16 + l15;
            float bc = bias[col];
            f32x4 r = acc[i][j];
#pragma unroll
            for (int g = 0; g < 4; ++g)
                Y[(size_t)(row + g) * NQKVS + col] = f2bf(r[g] + bc);
        }
    }
}

// ---------------- CSR build ----------------
__global__ __launch_bounds__(256) void k_hist(const int* __restrict__ dst, int* __restrict__ cnt)
{
    int e = blockIdx.x * blockDim.x + threadIdx.x;
    if (e < NEDGES) atomicAdd(&cnt[dst[e]], 1);
}

__global__ __launch_bounds__(256) void k_scan(const int* __restrict__ cnt, int* __restrict__ indptr)
{
    __shared__ int sums[256];
    __shared__ int offs[256];
    int t = threadIdx.x;
    int base = t * 32;
    int s = 0;
    for (int i = 0; i < 32; ++i) s += cnt[base + i];
    sums[t] = s;
    __syncthreads();
    if (t == 0) {
        int run = 0;
        for (int i = 0; i < 256; ++i) { offs[i] = run; run += sums[i]; }
    }
    __syncthreads();
    int off = offs[t];
    for (int i = 0; i < 32; ++i) { indptr[base + i] = off; off += cnt[base + i]; }
    if (t == 255) indptr[NNODES] = off;
}

__global__ __launch_bounds__(256) void k_scatter(
    const int* __restrict__ src, const int* __restrict__ dst,
    const int* __restrict__ indptr, int* __restrict__ cursor, int* __restrict__ ssrc)
{
    int e = blockIdx.x * blockDim.x + threadIdx.x;
    if (e >= NEDGES) return;
    int d = dst[e];
    int p = atomicAdd(&cursor[d], 1);
    ssrc[indptr[d] + p] = src[e];
}

// ---------------- per-node attention (1 wave/node, 4 nodes/block), bf16 ----------------
// lane l handles channels [l*8, l*8+8); heads are 8-lane groups (shfl_xor 1,2,4).
__global__ __launch_bounds__(256) void k_attn(
    const int* __restrict__ indptr, const int* __restrict__ ssrc,
    const ushort* __restrict__ Y,   // [N][2048] packed q|k|v|s
    ushort* __restrict__ X)         // [N][512] bf16 out
{
    int n = blockIdx.x * 4 + (threadIdx.x >> 6);
    if (n >= NNODES) return;
    int l = threadIdx.x & 63;
    int cbase = l * 8;
    const ushort* yq = Y + (size_t)n * NQKVS + cbase;
    float qf[8];
    {
        bf16x8 q8 = *(const bf16x8*)yq;
#pragma unroll
        for (int j = 0; j < 8; ++j) qf[j] = bf2f((ushort)q8[j]);
    }
    float mrun = -INFINITY, ssum = 0.f;
    float acc[8] = {};
    int e0 = indptr[n], e1 = indptr[n + 1];
    bf16x8 kN = {}, vN = {};
    if (e0 < e1) {
        int s = ssrc[e0];
        const ushort* yr = Y + (size_t)s * NQKVS + cbase;
        kN = *(const bf16x8*)(yr + 512);
        vN = *(const bf16x8*)(yr + 1024);
    }
    for (int e = e0; e < e1; ++e) {
        bf16x8 k8 = kN, v8 = vN;
        if (e + 1 < e1) {
            int s = ssrc[e + 1];
            const ushort* yr = Y + (size_t)s * NQKVS + cbase;
            kN = *(const bf16x8*)(yr + 512);
            vN = *(const bf16x8*)(yr + 1024);
        }
        float part = 0.f;
#pragma unroll
        for (int j = 0; j < 8; ++j) part = fmaf(qf[j], bf2f((ushort)k8[j]), part);
        part += __shfl_xor(part, 1);
        part += __shfl_xor(part, 2);
        part += __shfl_xor(part, 4);
        float score = part * 0.125f;            // / sqrt(64)
        float mnew = fmaxf(mrun, score);
        float sc = __expf(mrun - mnew);
        float p = __expf(score - mnew);
        ssum = ssum * sc + p;
#pragma unroll
        for (int j = 0; j < 8; ++j)
            acc[j] = fmaf(acc[j], sc, p * bf2f((ushort)v8[j]));
        mrun = mnew;
    }
    float inv = ssum > 0.f ? 1.f / ssum : 0.f;
    bf16x8 o8;
#pragma unroll
    for (int j = 0; j < 8; ++j) {
        float o = fmaxf(fmaf(acc[j], inv, bf2f(yq[1536 + j])), 0.f);  // + skip, ReLU
        o8[j] = (short)f2bf(o);
    }
    *(bf16x8*)(X + (size_t)n * HID + cbase) = o8;
}

// ---------------- pooling: xsum[u][c] = sum_m X[u*M+m][c] ----------------
__global__ __launch_bounds__(512) void k_pool(const ushort* __restrict__ X, float* __restrict__ xsum)
{
    int u = blockIdx.x;
    int c = threadIdx.x;
    const ushort* base = X + (size_t)u * MM * HID + c;
    float s = 0.f;
    for (int m = 0; m < MM; ++m) s += bf2f(base[(size_t)m * HID]);
    xsum[u * HID + c] = s;
}

// ---------------- uav_emb = xsum @ Wout + M*bout ----------------
__global__ __launch_bounds__(64) void k_emb(
    const float* __restrict__ xsum, const float* __restrict__ Wout,
    const float* __restrict__ bout, float* __restrict__ emb)
{
    int u = blockIdx.x, j = threadIdx.x;
    const float* xr = xsum + u * HID;
    float s = 0.f;
    for (int i = 0; i < HID; ++i) s = fmaf(xr[i], Wout[i * 64 + j], s);
    emb[u * 64 + j] = s + 512.0f * bout[j];
}

// ---------------- head ----------------
__global__ __launch_bounds__(128) void k_head(
    const float* __restrict__ uavs, const float* __restrict__ speeds,
    const float* __restrict__ emb,
    const float* __restrict__ Wc1, const float* __restrict__ bc1,
    const float* __restrict__ Wc2, const float* __restrict__ bc2,
    float* __restrict__ out)
{
    __shared__ float comb[67];
    __shared__ float red[128];
    int u = blockIdx.x, t = threadIdx.x;
    if (t < 2) comb[t] = uavs[u * 2 + t];
    else if (t < 66) comb[t] = emb[u * 64 + (t - 2)];
    else if (t == 66) comb[t] = speeds[u];
    __syncthreads();
    float a = bc1[t];
    for (int i = 0; i < 67; ++i) a = fmaf(comb[i], Wc1[i * 128 + t], a);
    a = fmaxf(a, 0.f);
    red[t] = a * Wc2[t];
    __syncthreads();
    for (int sft = 64; sft > 0; sft >>= 1) {
        if (t < sft) red[t] += red[t + sft];
        __syncthreads();
    }
    if (t == 0) {
        out[u]      = 1.0f;                 // softmax over singleton axis
        out[16 + u] = red[0] + bc2[0];
    }
}

extern "C" void kernel_launch(void* const* d_in, const int* in_sizes, int n_in,
                              void* d_out, int out_size, void* d_ws, size_t ws_size,
                              hipStream_t stream)
{
    const float* mission_coords = (const float*)d_in[0];
    const float* uavs_info      = (const float*)d_in[1];
    const float* speeds         = (const float*)d_in[2];
    const float* dist_matrix    = (const float*)d_in[3];
    const float* timetogo       = (const float*)d_in[4];
    const int*   action_mask    = (const int*)d_in[5];
    const int*   edge_index     = (const int*)d_in[6];
    const float* Wq0 = (const float*)d_in[8];  const float* bq0 = (const float*)d_in[9];
    const float* Wk0 = (const float*)d_in[10]; const float* bk0 = (const float*)d_in[11];
    const float* Wv0 = (const float*)d_in[12]; const float* bv0 = (const float*)d_in[13];
    const float* Ws0 = (const float*)d_in[14]; const float* bs0 = (const float*)d_in[15];
    const float* Wq  = (const float*)d_in[16]; const float* bq  = (const float*)d_in[17];
    const float* Wk  = (const float*)d_in[18]; const float* bk  = (const float*)d_in[19];
    const float* Wv  = (const float*)d_in[20]; const float* bv  = (const float*)d_in[21];
    const float* Ws  = (const float*)d_in[22]; const float* bs  = (const float*)d_in[23];
    const float* Wout = (const float*)d_in[24]; const float* bout = (const float*)d_in[25];
    const float* Wc1 = (const float*)d_in[30]; const float* bc1 = (const float*)d_in[31];
    const float* Wc2 = (const float*)d_in[32]; const float* bc2 = (const float*)d_in[33];
    float* out = (float*)d_out;

    const int* e_src = edge_index;
    const int* e_dst = edge_index + NEDGES;

    // ---- workspace carve ----
    char* p = (char*)d_ws;
    ushort* Ybf = (ushort*)p;  p += (size_t)NNODES * NQKVS * 2;   // 32 MB
    ushort* Xbf = (ushort*)p;  p += (size_t)NNODES * HID * 2;     // 8 MB
    ushort* Wt  = (ushort*)p;  p += (size_t)3 * NQKVS * HID * 2;  // 6 MB
    float* bcat = (float*)p;   p += (size_t)3 * NQKVS * 4;
    float* x6   = (float*)p;   p += (size_t)NNODES * 6 * 4;
    float* xsum = (float*)p;   p += (size_t)UU * HID * 4;
    float* emb  = (float*)p;   p += (size_t)UU * 64 * 4;
    int* cnt    = (int*)p;     p += (size_t)NNODES * 4;
    int* indptr = (int*)p;     p += (size_t)(NNODES + 1) * 4;
    int* cursor = (int*)p;     p += (size_t)NNODES * 4;
    int* ssrc   = (int*)p;     p += (size_t)NEDGES * 4;

    hipMemsetAsync(cnt, 0, NNODES * sizeof(int), stream);
    hipMemsetAsync(cursor, 0, NNODES * sizeof(int), stream);

    // ---- prep: features, weights, CSR ----
    k_build_x<<<NNODES / 256, 256, 0, stream>>>(mission_coords, speeds, dist_matrix,
                                                timetogo, action_mask, x6);
    k_wt<<<dim3(8, 8, 12), 256, 0, stream>>>(Wq, Wk, Wv, Ws, Wt);
    k_bias<<<3 * NQKVS / 256, 256, 0, stream>>>(bq, bk, bv, bs, bcat);
    k_hist<<<NEDGES / 256, 256, 0, stream>>>(e_dst, cnt);
    k_scan<<<1, 256, 0, stream>>>(cnt, indptr);
    k_scatter<<<NEDGES / 256, 256, 0, stream>>>(e_src, e_dst, indptr, cursor, ssrc);

    // ---- layer 0 (in=6) ----
    k_lin0<<<(size_t)NNODES * NQKVS / 256, 256, 0, stream>>>(
        x6, Wq0, bq0, Wk0, bk0, Wv0, bv0, Ws0, bs0, Ybf);
    k_attn<<<NNODES / 4, 256, 0, stream>>>(indptr, ssrc, Ybf, Xbf);

    // ---- layers 1..3: fused q|k|v|s MFMA GEMM + attention ----
    dim3 ggrid(NNODES / GBM, NQKVS / GBN);   // 32 x 8 = 256 blocks
    for (int l = 0; l < 3; ++l) {
        k_gemm<<<ggrid, 512, 0, stream>>>(Xbf, Wt + (size_t)l * NQKVS * HID,
                                          bcat + l * NQKVS, Ybf);
        k_attn<<<NNODES / 4, 256, 0, stream>>>(indptr, ssrc, Ybf, Xbf);
    }

    // ---- pooling + embedding + head ----
    k_pool<<<UU, 512, 0, stream>>>(Xbf, xsum);
    k_emb<<<UU, 64, 0, stream>>>(xsum, Wout, bout, emb);
    k_head<<<UU, 128, 0, stream>>>(uavs_info, speeds, emb, Wc1, bc1, Wc2, bc2, out);
}

// Round 4
// 309.159 us; speedup vs baseline: 3.5855x; 1.2426x over previous
//
#include <hip/hip_runtime.h>
#include <hip/hip_bf16.h>
#include <math.h>

#define NNODES 8192
#define NEDGES 131072
#define HID    512
#define UU     16
#define MM     512
#define NQKVS  2048   // packed q|k|v|s columns

typedef __attribute__((ext_vector_type(8))) short bf16x8;
typedef __attribute__((ext_vector_type(4))) float f32x4;

__device__ __forceinline__ float bf2f(ushort u) {
    return __uint_as_float(((unsigned)u) << 16);
}
__device__ __forceinline__ ushort f2bf(float f) {
    unsigned x = __float_as_uint(f);
    return (ushort)((x + 0x7fffu + ((x >> 16) & 1u)) >> 16);
}

// ---------------- feature build: x6[N][6] ----------------
__global__ __launch_bounds__(256) void k_build_x(
    const float* __restrict__ mc, const float* __restrict__ speeds,
    const float* __restrict__ dist, const float* __restrict__ ttg,
    const int* __restrict__ mask, float* __restrict__ x6)
{
    int n = blockIdx.x * blockDim.x + threadIdx.x;
    if (n >= NNODES) return;
    int u = n >> 9, m = n & 511;
    float* o = x6 + (size_t)n * 6;
    o[0] = mc[m * 2 + 0];
    o[1] = mc[m * 2 + 1];
    o[2] = (float)mask[u * MM + m];
    o[3] = speeds[u];
    o[4] = dist[u * MM + m];
    o[5] = ttg[u * MM + m];
}

// ---------------- weight transpose+convert: Wt[l][2048][512] bf16 ----------------
__global__ __launch_bounds__(256) void k_wt(
    const float* __restrict__ Wq, const float* __restrict__ Wk,
    const float* __restrict__ Wv, const float* __restrict__ Ws,
    ushort* __restrict__ Wt)
{
    __shared__ float tile[64][65];
    int z = blockIdx.z;                 // 12 matrices: l*4+which
    int l = z >> 2, which = z & 3;
    const float* src = (which == 0 ? Wq : which == 1 ? Wk : which == 2 ? Wv : Ws)
                       + (size_t)l * HID * HID;
    int k0 = blockIdx.x * 64, c0 = blockIdx.y * 64;
    int t = threadIdx.x;
#pragma unroll
    for (int i = 0; i < 16; ++i) {
        int idx = i * 256 + t;
        int r = idx >> 6, c = idx & 63;
        tile[r][c] = src[(size_t)(k0 + r) * HID + c0 + c];
    }
    __syncthreads();
    ushort* dst = Wt + ((size_t)l * NQKVS + which * HID + c0) * HID + k0;
#pragma unroll
    for (int i = 0; i < 16; ++i) {
        int idx = i * 256 + t;
        int r = idx >> 6, c = idx & 63;
        dst[(size_t)r * HID + c] = f2bf(tile[c][r]);
    }
}

// ---------------- bias pack: bcat[3][2048] ----------------
__global__ __launch_bounds__(256) void k_bias(
    const float* __restrict__ bq, const float* __restrict__ bk,
    const float* __restrict__ bv, const float* __restrict__ bs,
    float* __restrict__ bcat)
{
    int i = blockIdx.x * 256 + threadIdx.x;   // [3][2048]
    int l = i >> 11, j = i & 2047;
    int which = j >> 9, jj = j & 511;
    const float* b = which == 0 ? bq : which == 1 ? bk : which == 2 ? bv : bs;
    bcat[i] = b[l * HID + jj];
}

// ---------------- layer-0 linear (in=6), vectorized: 8 cols/thread ----------------
__global__ __launch_bounds__(256) void k_lin0(
    const float* __restrict__ x6,
    const float* __restrict__ Wq0, const float* __restrict__ bq0,
    const float* __restrict__ Wk0, const float* __restrict__ bk0,
    const float* __restrict__ Wv0, const float* __restrict__ bv0,
    const float* __restrict__ Ws0, const float* __restrict__ bs0,
    ushort* __restrict__ Y)
{
    int n = blockIdx.x;                // node
    int j = threadIdx.x;               // 0..255 -> cols j*8..j*8+7
    int col0 = j * 8;
    int which = col0 >> 9, jj = col0 & 511;
    const float* W = which == 0 ? Wq0 : which == 1 ? Wk0 : which == 2 ? Wv0 : Ws0;
    const float* b = which == 0 ? bq0 : which == 1 ? bk0 : which == 2 ? bv0 : bs0;
    const float* xr = x6 + (size_t)n * 6;
    float x[6];
#pragma unroll
    for (int t = 0; t < 6; ++t) x[t] = xr[t];
    float s[8];
#pragma unroll
    for (int u = 0; u < 8; ++u) s[u] = b[jj + u];
#pragma unroll
    for (int t = 0; t < 6; ++t)
#pragma unroll
        for (int u = 0; u < 8; ++u)
            s[u] = fmaf(x[t], W[t * HID + jj + u], s[u]);
    bf16x8 o8;
#pragma unroll
    for (int u = 0; u < 8; ++u) o8[u] = (short)f2bf(s[u]);
    *(bf16x8*)(Y + (size_t)n * NQKVS + col0) = o8;
}

// ---------------- bf16 MFMA GEMM: Y[8192][2048] = X[8192][512] @ Wt^T + bias ----------------
// 128x128 tile, BK=64, 4 waves (2x2), 64KB LDS double-buffered -> 2 blocks/CU.
// Staging: each gload_lds covers 8 rows x 128B contiguous (full cachelines).
// LDS linear [row][64k]; XOR swizzle (kq ^ row&7) applied on global SOURCE addr
// and on the ds_read index (both-sides, rule #21) -> conflict-free ds_read_b128.
#define GBM 128
#define GBN 128
#define GBK 64
#define TILEB (GBM * GBK * 2)   // 16384 B per matrix tile
#define BUFB  (2 * TILEB)       // 32768 B per buffer (A+B)

__device__ __forceinline__ void stage_tile(
    const ushort* __restrict__ Ag, const ushort* __restrict__ Bg,
    char* __restrict__ base, int t)
{
    const int lane = t & 63;
    const int w = t >> 6;           // wave 0..3
    const int r8 = lane >> 3;       // row within 8-row slab
    const int c  = lane & 7;        // col16 slot
    const int csw = c ^ r8;         // XOR-swizzled source col (r0 is mult of 8)
#pragma unroll
    for (int i = 0; i < 4; ++i) {
        int r0 = (w * 4 + i) * 8;   // 0,8,...,120
        __builtin_amdgcn_global_load_lds(
            (const __attribute__((address_space(1))) void*)(Ag + (size_t)(r0 + r8) * HID + csw * 8),
            (__attribute__((address_space(3))) void*)(base + r0 * 128 + lane * 16), 16, 0, 0);
        __builtin_amdgcn_global_load_lds(
            (const __attribute__((address_space(1))) void*)(Bg + (size_t)(r0 + r8) * HID + csw * 8),
            (__attribute__((address_space(3))) void*)(base + TILEB + r0 * 128 + lane * 16), 16, 0, 0);
    }
}

__global__ __launch_bounds__(256, 2) void k_gemm(
    const ushort* __restrict__ A,    // [8192][512] bf16
    const ushort* __restrict__ Bt,   // [2048][512] bf16 (weights, [n][k])
    const float* __restrict__ bias,  // [2048] fp32
    ushort* __restrict__ Y)          // [8192][2048] bf16
{
    __shared__ char lds[2 * BUFB];   // 65536 B
    const int t = threadIdx.x;
    const int m0 = blockIdx.x * GBM, n0 = blockIdx.y * GBN;
    const int wid = t >> 6, lane = t & 63;
    const int wr = wid >> 1, wc = wid & 1;      // 2x2 waves, 64x64 out each
    const int l15 = lane & 15, lkq = lane >> 4;

    f32x4 acc[4][4] = {};

    const ushort* Ab = A + (size_t)m0 * HID;
    const ushort* Bb = Bt + (size_t)n0 * HID;

    stage_tile(Ab, Bb, lds, t);
    int cur = 0;
    const int NKS = HID / GBK;   // 8
    for (int T = 0; T < NKS; ++T) {
        __syncthreads();         // drains stage of buf[cur]; protects buf[cur^1] rewrite
        if (T + 1 < NKS)
            stage_tile(Ab + (T + 1) * GBK, Bb + (T + 1) * GBK,
                       lds + (cur ^ 1) * BUFB, t);
        const char* la = lds + cur * BUFB;
        const char* lb = la + TILEB;
#pragma unroll
        for (int kh = 0; kh < 2; ++kh) {
            const int kq = kh * 4 + lkq;
            const int sw = (kq ^ (l15 & 7)) << 4;
            bf16x8 a[4], b[4];
#pragma unroll
            for (int i = 0; i < 4; ++i)
                a[i] = *(const bf16x8*)(la + (wr * 64 + i * 16 + l15) * 128 + sw);
#pragma unroll
            for (int j = 0; j < 4; ++j)
                b[j] = *(const bf16x8*)(lb + (wc * 64 + j * 16 + l15) * 128 + sw);
#pragma unroll
            for (int i = 0; i < 4; ++i)
#pragma unroll
                for (int j = 0; j < 4; ++j)
                    acc[i][j] = __builtin_amdgcn_mfma_f32_16x16x32_bf16(a[i], b[j], acc[i][j], 0, 0, 0);
        }
        cur ^= 1;
    }

    // epilogue: C/D layout col=lane&15, row=(lane>>4)*4+reg
#pragma unroll
    for (int i = 0; i < 4; ++i) {
        int row = m0 + wr * 64 + i * 16 + lkq * 4;
#pragma unroll
        for (int j = 0; j < 4; ++j) {
            int col = n0 + wc * 64 + j * 16 + l15;
            float bc = bias[col];
            f32x4 r = acc[i][j];
#pragma unroll
            for (int g = 0; g < 4; ++g)
                Y[(size_t)(row + g) * NQKVS + col] = f2bf(r[g] + bc);
        }
    }
}

// ---------------- CSR build ----------------
__global__ __launch_bounds__(256) void k_hist(const int* __restrict__ dst, int* __restrict__ cnt)
{
    int e = blockIdx.x * blockDim.x + threadIdx.x;
    if (e < NEDGES) atomicAdd(&cnt[dst[e]], 1);
}

__global__ __launch_bounds__(256) void k_scan(const int* __restrict__ cnt, int* __restrict__ indptr)
{
    __shared__ int sums[256];
    __shared__ int offs[256];
    int t = threadIdx.x;
    int base = t * 32;
    int s = 0;
    for (int i = 0; i < 32; ++i) s += cnt[base + i];
    sums[t] = s;
    __syncthreads();
    if (t == 0) {
        int run = 0;
        for (int i = 0; i < 256; ++i) { offs[i] = run; run += sums[i]; }
    }
    __syncthreads();
    int off = offs[t];
    for (int i = 0; i < 32; ++i) { indptr[base + i] = off; off += cnt[base + i]; }
    if (t == 255) indptr[NNODES] = off;
}

__global__ __launch_bounds__(256) void k_scatter(
    const int* __restrict__ src, const int* __restrict__ dst,
    const int* __restrict__ indptr, int* __restrict__ cursor, int* __restrict__ ssrc)
{
    int e = blockIdx.x * blockDim.x + threadIdx.x;
    if (e >= NEDGES) return;
    int d = dst[e];
    int p = atomicAdd(&cursor[d], 1);
    ssrc[indptr[d] + p] = src[e];
}

// ---------------- per-node attention (1 wave/node, 4 nodes/block), 2-deep prefetch ----------------
// lane l handles channels [l*8, l*8+8); heads are 8-lane groups (shfl_xor 1,2,4).
__global__ __launch_bounds__(256) void k_attn(
    const int* __restrict__ indptr, const int* __restrict__ ssrc,
    const ushort* __restrict__ Y,   // [N][2048] packed q|k|v|s
    ushort* __restrict__ X)         // [N][512] bf16 out
{
    int n = blockIdx.x * 4 + (threadIdx.x >> 6);
    if (n >= NNODES) return;
    int l = threadIdx.x & 63;
    int cbase = l * 8;
    const ushort* yq = Y + (size_t)n * NQKVS + cbase;
    float qf[8];
    {
        bf16x8 q8 = *(const bf16x8*)yq;
#pragma unroll
        for (int j = 0; j < 8; ++j) qf[j] = bf2f((ushort)q8[j]);
    }
    float mrun = -INFINITY, ssum = 0.f;
    float acc[8] = {};
    int e0 = indptr[n], e1 = indptr[n + 1];
    bf16x8 ka = {}, va = {}, kb = {}, vb = {};
    if (e0 < e1) {
        int s = ssrc[e0];
        const ushort* yr = Y + (size_t)s * NQKVS + cbase;
        ka = *(const bf16x8*)(yr + 512);
        va = *(const bf16x8*)(yr + 1024);
    }
    if (e0 + 1 < e1) {
        int s = ssrc[e0 + 1];
        const ushort* yr = Y + (size_t)s * NQKVS + cbase;
        kb = *(const bf16x8*)(yr + 512);
        vb = *(const bf16x8*)(yr + 1024);
    }
    for (int e = e0; e < e1; ++e) {
        bf16x8 k8 = ka, v8 = va;
        ka = kb; va = vb;
        int en = e + 2;
        if (en < e1) {
            int s = ssrc[en];
            const ushort* yr = Y + (size_t)s * NQKVS + cbase;
            kb = *(const bf16x8*)(yr + 512);
            vb = *(const bf16x8*)(yr + 1024);
        }
        float part = 0.f;
#pragma unroll
        for (int j = 0; j < 8; ++j) part = fmaf(qf[j], bf2f((ushort)k8[j]), part);
        part += __shfl_xor(part, 1);
        part += __shfl_xor(part, 2);
        part += __shfl_xor(part, 4);
        float score = part * 0.125f;            // / sqrt(64)
        float mnew = fmaxf(mrun, score);
        float sc = __expf(mrun - mnew);
        float p = __expf(score - mnew);
        ssum = ssum * sc + p;
#pragma unroll
        for (int j = 0; j < 8; ++j)
            acc[j] = fmaf(acc[j], sc, p * bf2f((ushort)v8[j]));
        mrun = mnew;
    }
    float inv = ssum > 0.f ? 1.f / ssum : 0.f;
    bf16x8 o8;
#pragma unroll
    for (int j = 0; j < 8; ++j) {
        float o = fmaxf(fmaf(acc[j], inv, bf2f(yq[1536 + j])), 0.f);  // + skip, ReLU
        o8[j] = (short)f2bf(o);
    }
    *(bf16x8*)(X + (size_t)n * HID + cbase) = o8;
}

// ---------------- pooling: xsum[u][c] = sum_m X[u*M+m][c] ----------------
__global__ __launch_bounds__(512) void k_pool(const ushort* __restrict__ X, float* __restrict__ xsum)
{
    int u = blockIdx.x;
    int c = threadIdx.x;
    const ushort* base = X + (size_t)u * MM * HID + c;
    float s = 0.f;
    for (int m = 0; m < MM; ++m) s += bf2f(base[(size_t)m * HID]);
    xsum[u * HID + c] = s;
}

// ---------------- uav_emb = xsum @ Wout + M*bout ----------------
__global__ __launch_bounds__(64) void k_emb(
    const float* __restrict__ xsum, const float* __restrict__ Wout,
    const float* __restrict__ bout, float* __restrict__ emb)
{
    int u = blockIdx.x, j = threadIdx.x;
    const float* xr = xsum + u * HID;
    float s = 0.f;
    for (int i = 0; i < HID; ++i) s = fmaf(xr[i], Wout[i * 64 + j], s);
    emb[u * 64 + j] = s + 512.0f * bout[j];
}

// ---------------- head ----------------
__global__ __launch_bounds__(128) void k_head(
    const float* __restrict__ uavs, const float* __restrict__ speeds,
    const float* __restrict__ emb,
    const float* __restrict__ Wc1, const float* __restrict__ bc1,
    const float* __restrict__ Wc2, const float* __restrict__ bc2,
    float* __restrict__ out)
{
    __shared__ float comb[67];
    __shared__ float red[128];
    int u = blockIdx.x, t = threadIdx.x;
    if (t < 2) comb[t] = uavs[u * 2 + t];
    else if (t < 66) comb[t] = emb[u * 64 + (t - 2)];
    else if (t == 66) comb[t] = speeds[u];
    __syncthreads();
    float a = bc1[t];
    for (int i = 0; i < 67; ++i) a = fmaf(comb[i], Wc1[i * 128 + t], a);
    a = fmaxf(a, 0.f);
    red[t] = a * Wc2[t];
    __syncthreads();
    for (int sft = 64; sft > 0; sft >>= 1) {
        if (t < sft) red[t] += red[t + sft];
        __syncthreads();
    }
    if (t == 0) {
        out[u]      = 1.0f;                 // softmax over singleton axis
        out[16 + u] = red[0] + bc2[0];
    }
}

extern "C" void kernel_launch(void* const* d_in, const int* in_sizes, int n_in,
                              void* d_out, int out_size, void* d_ws, size_t ws_size,
                              hipStream_t stream)
{
    const float* mission_coords = (const float*)d_in[0];
    const float* uavs_info      = (const float*)d_in[1];
    const float* speeds         = (const float*)d_in[2];
    const float* dist_matrix    = (const float*)d_in[3];
    const float* timetogo       = (const float*)d_in[4];
    const int*   action_mask    = (const int*)d_in[5];
    const int*   edge_index     = (const int*)d_in[6];
    const float* Wq0 = (const float*)d_in[8];  const float* bq0 = (const float*)d_in[9];
    const float* Wk0 = (const float*)d_in[10]; const float* bk0 = (const float*)d_in[11];
    const float* Wv0 = (const float*)d_in[12]; const float* bv0 = (const float*)d_in[13];
    const float* Ws0 = (const float*)d_in[14]; const float* bs0 = (const float*)d_in[15];
    const float* Wq  = (const float*)d_in[16]; const float* bq  = (const float*)d_in[17];
    const float* Wk  = (const float*)d_in[18]; const float* bk  = (const float*)d_in[19];
    const float* Wv  = (const float*)d_in[20]; const float* bv  = (const float*)d_in[21];
    const float* Ws  = (const float*)d_in[22]; const float* bs  = (const float*)d_in[23];
    const float* Wout = (const float*)d_in[24]; const float* bout = (const float*)d_in[25];
    const float* Wc1 = (const float*)d_in[30]; const float* bc1 = (const float*)d_in[31];
    const float* Wc2 = (const float*)d_in[32]; const float* bc2 = (const float*)d_in[33];
    float* out = (float*)d_out;

    const int* e_src = edge_index;
    const int* e_dst = edge_index + NEDGES;

    // ---- workspace carve ----
    char* p = (char*)d_ws;
    ushort* Ybf = (ushort*)p;  p += (size_t)NNODES * NQKVS * 2;   // 32 MB
    ushort* Xbf = (ushort*)p;  p += (size_t)NNODES * HID * 2;     // 8 MB
    ushort* Wt  = (ushort*)p;  p += (size_t)3 * NQKVS * HID * 2;  // 6 MB
    float* bcat = (float*)p;   p += (size_t)3 * NQKVS * 4;
    float* x6   = (float*)p;   p += (size_t)NNODES * 6 * 4;
    float* xsum = (float*)p;   p += (size_t)UU * HID * 4;
    float* emb  = (float*)p;   p += (size_t)UU * 64 * 4;
    int* cnt    = (int*)p;     p += (size_t)NNODES * 4;
    int* indptr = (int*)p;     p += (size_t)(NNODES + 1) * 4;
    int* cursor = (int*)p;     p += (size_t)NNODES * 4;
    int* ssrc   = (int*)p;     p += (size_t)NEDGES * 4;

    hipMemsetAsync(cnt, 0, NNODES * sizeof(int), stream);
    hipMemsetAsync(cursor, 0, NNODES * sizeof(int), stream);

    // ---- prep: features, weights, CSR ----
    k_build_x<<<NNODES / 256, 256, 0, stream>>>(mission_coords, speeds, dist_matrix,
                                                timetogo, action_mask, x6);
    k_wt<<<dim3(8, 8, 12), 256, 0, stream>>>(Wq, Wk, Wv, Ws, Wt);
    k_bias<<<3 * NQKVS / 256, 256, 0, stream>>>(bq, bk, bv, bs, bcat);
    k_hist<<<NEDGES / 256, 256, 0, stream>>>(e_dst, cnt);
    k_scan<<<1, 256, 0, stream>>>(cnt, indptr);
    k_scatter<<<NEDGES / 256, 256, 0, stream>>>(e_src, e_dst, indptr, cursor, ssrc);

    // ---- layer 0 (in=6) ----
    k_lin0<<<NNODES, 256, 0, stream>>>(x6, Wq0, bq0, Wk0, bk0, Wv0, bv0, Ws0, bs0, Ybf);
    k_attn<<<NNODES / 4, 256, 0, stream>>>(indptr, ssrc, Ybf, Xbf);

    // ---- layers 1..3: fused q|k|v|s MFMA GEMM + attention ----
    dim3 ggrid(NNODES / GBM, NQKVS / GBN);   // 64 x 16 = 1024 blocks
    for (int l = 0; l < 3; ++l) {
        k_gemm<<<ggrid, 256, 0, stream>>>(Xbf, Wt + (size_t)l * NQKVS * HID,
                                          bcat + l * NQKVS, Ybf);
        k_attn<<<NNODES / 4, 256, 0, stream>>>(indptr, ssrc, Ybf, Xbf);
    }

    // ---- pooling + embedding + head ----
    k_pool<<<UU, 512, 0, stream>>>(Xbf, xsum);
    k_emb<<<UU, 64, 0, stream>>>(xsum, Wout, bout, emb);
    k_head<<<UU, 128, 0, stream>>>(uavs_info, speeds, emb, Wc1, bc1, Wc2, bc2, out);
}

// Round 5
// 277.263 us; speedup vs baseline: 3.9979x; 1.1150x over previous
//
#include <hip/hip_runtime.h>
#include <hip/hip_bf16.h>
#include <math.h>

#define NNODES 8192
#define NEDGES 131072
#define HID    512
#define UU     16
#define MM     512
#define NQKVS  2048   // packed q|k|v|s columns

#if __has_builtin(__builtin_amdgcn_cvt_pk_f32_fp8) && __has_builtin(__builtin_amdgcn_cvt_pk_fp8_f32)
#define HAVE_FP8 1
#else
#define HAVE_FP8 0
#endif

#define KSCALE 16.0f
#define KISCALE (0.125f / 16.0f)   // score = (q . 16k) * 0.125/16

typedef __attribute__((ext_vector_type(8))) short bf16x8;
typedef __attribute__((ext_vector_type(4))) float f32x4;
typedef __attribute__((ext_vector_type(2))) float f32x2;

__device__ __forceinline__ float bf2f(ushort u) {
    return __uint_as_float(((unsigned)u) << 16);
}
__device__ __forceinline__ ushort f2bf(float f) {
    unsigned x = __float_as_uint(f);
    return (ushort)((x + 0x7fffu + ((x >> 16) & 1u)) >> 16);
}

// ---------------- feature build: x6[N][6] ----------------
__global__ __launch_bounds__(256) void k_build_x(
    const float* __restrict__ mc, const float* __restrict__ speeds,
    const float* __restrict__ dist, const float* __restrict__ ttg,
    const int* __restrict__ mask, float* __restrict__ x6)
{
    int n = blockIdx.x * blockDim.x + threadIdx.x;
    if (n >= NNODES) return;
    int u = n >> 9, m = n & 511;
    float* o = x6 + (size_t)n * 6;
    o[0] = mc[m * 2 + 0];
    o[1] = mc[m * 2 + 1];
    o[2] = (float)mask[u * MM + m];
    o[3] = speeds[u];
    o[4] = dist[u * MM + m];
    o[5] = ttg[u * MM + m];
}

// ---------------- weight transpose+convert: Wt[l][2048][512] bf16 ----------------
__global__ __launch_bounds__(256) void k_wt(
    const float* __restrict__ Wq, const float* __restrict__ Wk,
    const float* __restrict__ Wv, const float* __restrict__ Ws,
    ushort* __restrict__ Wt)
{
    __shared__ float tile[64][65];
    int z = blockIdx.z;                 // 12 matrices: l*4+which
    int l = z >> 2, which = z & 3;
    const float* src = (which == 0 ? Wq : which == 1 ? Wk : which == 2 ? Wv : Ws)
                       + (size_t)l * HID * HID;
    int k0 = blockIdx.x * 64, c0 = blockIdx.y * 64;
    int t = threadIdx.x;
#pragma unroll
    for (int i = 0; i < 16; ++i) {
        int idx = i * 256 + t;
        int r = idx >> 6, c = idx & 63;
        tile[r][c] = src[(size_t)(k0 + r) * HID + c0 + c];
    }
    __syncthreads();
    ushort* dst = Wt + ((size_t)l * NQKVS + which * HID + c0) * HID + k0;
#pragma unroll
    for (int i = 0; i < 16; ++i) {
        int idx = i * 256 + t;
        int r = idx >> 6, c = idx & 63;
        dst[(size_t)r * HID + c] = f2bf(tile[c][r]);
    }
}

// ---------------- bias pack: bcat[3][2048] ----------------
__global__ __launch_bounds__(256) void k_bias(
    const float* __restrict__ bq, const float* __restrict__ bk,
    const float* __restrict__ bv, const float* __restrict__ bs,
    float* __restrict__ bcat)
{
    int i = blockIdx.x * 256 + threadIdx.x;   // [3][2048]
    int l = i >> 11, j = i & 2047;
    int which = j >> 9, jj = j & 511;
    const float* b = which == 0 ? bq : which == 1 ? bk : which == 2 ? bv : bs;
    bcat[i] = b[l * HID + jj];
}

// ---------------- layer-0 linear (in=6), vectorized: 8 cols/thread ----------------
__global__ __launch_bounds__(256) void k_lin0(
    const float* __restrict__ x6,
    const float* __restrict__ Wq0, const float* __restrict__ bq0,
    const float* __restrict__ Wk0, const float* __restrict__ bk0,
    const float* __restrict__ Wv0, const float* __restrict__ bv0,
    const float* __restrict__ Ws0, const float* __restrict__ bs0,
    ushort* __restrict__ Y, unsigned char* __restrict__ Kf8)
{
    int n = blockIdx.x;                // node
    int j = threadIdx.x;               // 0..255 -> cols j*8..j*8+7
    int col0 = j * 8;
    int which = col0 >> 9, jj = col0 & 511;
    const float* W = which == 0 ? Wq0 : which == 1 ? Wk0 : which == 2 ? Wv0 : Ws0;
    const float* b = which == 0 ? bq0 : which == 1 ? bk0 : which == 2 ? bv0 : bs0;
    const float* xr = x6 + (size_t)n * 6;
    float x[6];
#pragma unroll
    for (int t = 0; t < 6; ++t) x[t] = xr[t];
    float s[8];
#pragma unroll
    for (int u = 0; u < 8; ++u) s[u] = b[jj + u];
#pragma unroll
    for (int t = 0; t < 6; ++t)
#pragma unroll
        for (int u = 0; u < 8; ++u)
            s[u] = fmaf(x[t], W[t * HID + jj + u], s[u]);
    bf16x8 o8;
#pragma unroll
    for (int u = 0; u < 8; ++u) o8[u] = (short)f2bf(s[u]);
    *(bf16x8*)(Y + (size_t)n * NQKVS + col0) = o8;
#if HAVE_FP8
    if (which == 1) {   // k quarter -> fp8 copy (scaled)
        int w0 = __builtin_amdgcn_cvt_pk_fp8_f32(s[0] * KSCALE, s[1] * KSCALE, 0, false);
        w0     = __builtin_amdgcn_cvt_pk_fp8_f32(s[2] * KSCALE, s[3] * KSCALE, w0, true);
        int w1 = __builtin_amdgcn_cvt_pk_fp8_f32(s[4] * KSCALE, s[5] * KSCALE, 0, false);
        w1     = __builtin_amdgcn_cvt_pk_fp8_f32(s[6] * KSCALE, s[7] * KSCALE, w1, true);
        uint2 uu; uu.x = (unsigned)w0; uu.y = (unsigned)w1;
        *(uint2*)(Kf8 + (size_t)n * HID + jj) = uu;
    }
#endif
}

// ---------------- bf16 MFMA GEMM: Y[8192][2048] = X[8192][512] @ Wt^T + bias ----------------
// 128x128 tile, BK=64, 4 waves (2x2), 64KB LDS double-buffered -> 2 blocks/CU.
// Staging: each gload_lds covers 8 rows x 128B contiguous (full cachelines).
// XOR swizzle (kq ^ row&7) on global SOURCE addr + ds_read index (rule #21).
// XCD-aware bijective block remap: xcd = bid&7 owns m-band [xcd*8, xcd*8+8),
// n varies outer within the band -> per-XCD working set A-band(1MB)+B(2MB) < 4MB L2.
#define GBM 128
#define GBN 128
#define GBK 64
#define TILEB (GBM * GBK * 2)   // 16384 B per matrix tile
#define BUFB  (2 * TILEB)       // 32768 B per buffer (A+B)

__device__ __forceinline__ void stage_tile(
    const ushort* __restrict__ Ag, const ushort* __restrict__ Bg,
    char* __restrict__ base, int t)
{
    const int lane = t & 63;
    const int w = t >> 6;           // wave 0..3
    const int r8 = lane >> 3;       // row within 8-row slab
    const int c  = lane & 7;        // col16 slot
    const int csw = c ^ r8;         // XOR-swizzled source col (r0 is mult of 8)
#pragma unroll
    for (int i = 0; i < 4; ++i) {
        int r0 = (w * 4 + i) * 8;   // 0,8,...,120
        __builtin_amdgcn_global_load_lds(
            (const __attribute__((address_space(1))) void*)(Ag + (size_t)(r0 + r8) * HID + csw * 8),
            (__attribute__((address_space(3))) void*)(base + r0 * 128 + lane * 16), 16, 0, 0);
        __builtin_amdgcn_global_load_lds(
            (const __attribute__((address_space(1))) void*)(Bg + (size_t)(r0 + r8) * HID + csw * 8),
            (__attribute__((address_space(3))) void*)(base + TILEB + r0 * 128 + lane * 16), 16, 0, 0);
    }
}

__global__ __launch_bounds__(256, 2) void k_gemm(
    const ushort* __restrict__ A,    // [8192][512] bf16
    const ushort* __restrict__ Bt,   // [2048][512] bf16 (weights, [n][k])
    const float* __restrict__ bias,  // [2048] fp32
    ushort* __restrict__ Y,          // [8192][2048] bf16
    unsigned char* __restrict__ Kf8) // [8192][512] fp8 (k quarter, scaled)
{
    __shared__ char lds[2 * BUFB];   // 65536 B
    const int t = threadIdx.x;
    // bijective XCD remap (1024 blocks, 8 XCDs, m-band per XCD)
    const int bid = blockIdx.x;
    const int xcd = bid & 7;
    const int ii  = bid >> 3;                 // 0..127
    const int mi  = (xcd << 3) | (ii & 7);    // 0..63
    const int ni  = ii >> 3;                  // 0..15
    const int m0 = mi * GBM, n0 = ni * GBN;

    const int wid = t >> 6, lane = t & 63;
    const int wr = wid >> 1, wc = wid & 1;      // 2x2 waves, 64x64 out each
    const int l15 = lane & 15, lkq = lane >> 4;

    f32x4 acc[4][4] = {};

    const ushort* Ab = A + (size_t)m0 * HID;
    const ushort* Bb = Bt + (size_t)n0 * HID;

    stage_tile(Ab, Bb, lds, t);
    int cur = 0;
    const int NKS = HID / GBK;   // 8
    for (int T = 0; T < NKS; ++T) {
        __syncthreads();         // drains stage of buf[cur]; protects buf[cur^1] rewrite
        if (T + 1 < NKS)
            stage_tile(Ab + (T + 1) * GBK, Bb + (T + 1) * GBK,
                       lds + (cur ^ 1) * BUFB, t);
        const char* la = lds + cur * BUFB;
        const char* lb = la + TILEB;
#pragma unroll
        for (int kh = 0; kh < 2; ++kh) {
            const int kq = kh * 4 + lkq;
            const int sw = (kq ^ (l15 & 7)) << 4;
            bf16x8 a[4], b[4];
#pragma unroll
            for (int i = 0; i < 4; ++i)
                a[i] = *(const bf16x8*)(la + (wr * 64 + i * 16 + l15) * 128 + sw);
#pragma unroll
            for (int j = 0; j < 4; ++j)
                b[j] = *(const bf16x8*)(lb + (wc * 64 + j * 16 + l15) * 128 + sw);
#pragma unroll
            for (int i = 0; i < 4; ++i)
#pragma unroll
                for (int j = 0; j < 4; ++j)
                    acc[i][j] = __builtin_amdgcn_mfma_f32_16x16x32_bf16(a[i], b[j], acc[i][j], 0, 0, 0);
        }
        cur ^= 1;
    }

    const bool kquad = ((n0 >> 9) == 1);   // cols [512,1024) = k quarter
    // epilogue: C/D layout col=lane&15, row=(lane>>4)*4+reg
#pragma unroll
    for (int i = 0; i < 4; ++i) {
        int row = m0 + wr * 64 + i * 16 + lkq * 4;
#pragma unroll
        for (int j = 0; j < 4; ++j) {
            int col = n0 + wc * 64 + j * 16 + l15;
            float bc = bias[col];
            f32x4 r = acc[i][j];
#pragma unroll
            for (int g = 0; g < 4; ++g) {
                float val = r[g] + bc;
                Y[(size_t)(row + g) * NQKVS + col] = f2bf(val);
#if HAVE_FP8
                if (kquad) {
                    int pk = __builtin_amdgcn_cvt_pk_fp8_f32(val * KSCALE, val * KSCALE, 0, false);
                    Kf8[(size_t)(row + g) * HID + (col - 512)] = (unsigned char)(pk & 0xff);
                }
#endif
            }
        }
    }
}

// ---------------- CSR build ----------------
__global__ __launch_bounds__(256) void k_hist(const int* __restrict__ dst, int* __restrict__ cnt)
{
    int e = blockIdx.x * blockDim.x + threadIdx.x;
    if (e < NEDGES) atomicAdd(&cnt[dst[e]], 1);
}

__global__ __launch_bounds__(256) void k_scan(const int* __restrict__ cnt, int* __restrict__ indptr)
{
    __shared__ int sums[256];
    __shared__ int offs[256];
    int t = threadIdx.x;
    int base = t * 32;
    int s = 0;
    for (int i = 0; i < 32; ++i) s += cnt[base + i];
    sums[t] = s;
    __syncthreads();
    if (t == 0) {
        int run = 0;
        for (int i = 0; i < 256; ++i) { offs[i] = run; run += sums[i]; }
    }
    __syncthreads();
    int off = offs[t];
    for (int i = 0; i < 32; ++i) { indptr[base + i] = off; off += cnt[base + i]; }
    if (t == 255) indptr[NNODES] = off;
}

__global__ __launch_bounds__(256) void k_scatter(
    const int* __restrict__ src, const int* __restrict__ dst,
    const int* __restrict__ indptr, int* __restrict__ cursor, int* __restrict__ ssrc)
{
    int e = blockIdx.x * blockDim.x + threadIdx.x;
    if (e >= NEDGES) return;
    int d = dst[e];
    int p = atomicAdd(&cursor[d], 1);
    ssrc[indptr[d] + p] = src[e];
}

// ---------------- per-node attention (1 wave/node, 4 nodes/block), 2-deep prefetch ----------------
// lane l handles channels [l*8, l*8+8); heads are 8-lane groups (shfl_xor 1,2,4).
// k gathered from fp8 (scaled x16), v from bf16 Y.
__global__ __launch_bounds__(256) void k_attn(
    const int* __restrict__ indptr, const int* __restrict__ ssrc,
    const ushort* __restrict__ Y,   // [N][2048] packed q|k|v|s
    const unsigned char* __restrict__ Kf8,  // [N][512] fp8
    ushort* __restrict__ X)         // [N][512] bf16 out
{
    int n = blockIdx.x * 4 + (threadIdx.x >> 6);
    if (n >= NNODES) return;
    int l = threadIdx.x & 63;
    int cbase = l * 8;
    const ushort* yq = Y + (size_t)n * NQKVS + cbase;
    float qf[8];
    {
        bf16x8 q8 = *(const bf16x8*)yq;
#pragma unroll
        for (int j = 0; j < 8; ++j) qf[j] = bf2f((ushort)q8[j]);
    }
    float mrun = -INFINITY, ssum = 0.f;
    float acc[8] = {};
    int e0 = indptr[n], e1 = indptr[n + 1];
#if HAVE_FP8
    uint2 ka = {}, kb = {};
#else
    bf16x8 ka = {}, kb = {};
#endif
    bf16x8 va = {}, vb = {};
    if (e0 < e1) {
        int s = ssrc[e0];
#if HAVE_FP8
        ka = *(const uint2*)(Kf8 + (size_t)s * HID + cbase);
#else
        ka = *(const bf16x8*)(Y + (size_t)s * NQKVS + 512 + cbase);
#endif
        va = *(const bf16x8*)(Y + (size_t)s * NQKVS + 1024 + cbase);
    }
    if (e0 + 1 < e1) {
        int s = ssrc[e0 + 1];
#if HAVE_FP8
        kb = *(const uint2*)(Kf8 + (size_t)s * HID + cbase);
#else
        kb = *(const bf16x8*)(Y + (size_t)s * NQKVS + 512 + cbase);
#endif
        vb = *(const bf16x8*)(Y + (size_t)s * NQKVS + 1024 + cbase);
    }
    for (int e = e0; e < e1; ++e) {
        auto k8 = ka; bf16x8 v8 = va;
        ka = kb; va = vb;
        int en = e + 2;
        if (en < e1) {
            int s = ssrc[en];
#if HAVE_FP8
            kb = *(const uint2*)(Kf8 + (size_t)s * HID + cbase);
#else
            kb = *(const bf16x8*)(Y + (size_t)s * NQKVS + 512 + cbase);
#endif
            vb = *(const bf16x8*)(Y + (size_t)s * NQKVS + 1024 + cbase);
        }
        float part = 0.f;
#if HAVE_FP8
        {
            f32x2 k01 = __builtin_amdgcn_cvt_pk_f32_fp8((int)k8.x, false);
            f32x2 k23 = __builtin_amdgcn_cvt_pk_f32_fp8((int)k8.x, true);
            f32x2 k45 = __builtin_amdgcn_cvt_pk_f32_fp8((int)k8.y, false);
            f32x2 k67 = __builtin_amdgcn_cvt_pk_f32_fp8((int)k8.y, true);
            part = fmaf(qf[0], k01.x, part); part = fmaf(qf[1], k01.y, part);
            part = fmaf(qf[2], k23.x, part); part = fmaf(qf[3], k23.y, part);
            part = fmaf(qf[4], k45.x, part); part = fmaf(qf[5], k45.y, part);
            part = fmaf(qf[6], k67.x, part); part = fmaf(qf[7], k67.y, part);
        }
#else
#pragma unroll
        for (int j = 0; j < 8; ++j) part = fmaf(qf[j], bf2f((ushort)k8[j]), part);
#endif
        part += __shfl_xor(part, 1);
        part += __shfl_xor(part, 2);
        part += __shfl_xor(part, 4);
#if HAVE_FP8
        float score = part * KISCALE;           // / (sqrt(64) * KSCALE)
#else
        float score = part * 0.125f;            // / sqrt(64)
#endif
        float mnew = fmaxf(mrun, score);
        float sc = __expf(mrun - mnew);
        float p = __expf(score - mnew);
        ssum = ssum * sc + p;
#pragma unroll
        for (int j = 0; j < 8; ++j)
            acc[j] = fmaf(acc[j], sc, p * bf2f((ushort)v8[j]));
        mrun = mnew;
    }
    float inv = ssum > 0.f ? 1.f / ssum : 0.f;
    bf16x8 o8;
#pragma unroll
    for (int j = 0; j < 8; ++j) {
        float o = fmaxf(fmaf(acc[j], inv, bf2f(yq[1536 + j])), 0.f);  // + skip, ReLU
        o8[j] = (short)f2bf(o);
    }
    *(bf16x8*)(X + (size_t)n * HID + cbase) = o8;
}

// ---------------- pooling: xsumP[u][p][c] = partial sums over 64 rows ----------------
__global__ __launch_bounds__(512) void k_pool(const ushort* __restrict__ X, float* __restrict__ xsumP)
{
    int u = blockIdx.x;
    int pp = blockIdx.y;               // 0..7
    int c = threadIdx.x;
    const ushort* base = X + ((size_t)u * MM + pp * 64) * HID + c;
    float s = 0.f;
    for (int m = 0; m < 64; ++m) s += bf2f(base[(size_t)m * HID]);
    xsumP[((size_t)u * 8 + pp) * HID + c] = s;
}

// ---------------- uav_emb = xsum @ Wout + M*bout (reduces 8 partials first) ----------------
__global__ __launch_bounds__(512) void k_emb(
    const float* __restrict__ xsumP, const float* __restrict__ Wout,
    const float* __restrict__ bout, float* __restrict__ emb)
{
    __shared__ float xs[HID];
    int u = blockIdx.x, c = threadIdx.x;
    float s = 0.f;
#pragma unroll
    for (int p = 0; p < 8; ++p) s += xsumP[((size_t)u * 8 + p) * HID + c];
    xs[c] = s;
    __syncthreads();
    if (c < 64) {
        float a = 0.f;
        for (int i = 0; i < HID; ++i) a = fmaf(xs[i], Wout[i * 64 + c], a);
        emb[u * 64 + c] = a + 512.0f * bout[c];
    }
}

// ---------------- head ----------------
__global__ __launch_bounds__(128) void k_head(
    const float* __restrict__ uavs, const float* __restrict__ speeds,
    const float* __restrict__ emb,
    const float* __restrict__ Wc1, const float* __restrict__ bc1,
    const float* __restrict__ Wc2, const float* __restrict__ bc2,
    float* __restrict__ out)
{
    __shared__ float comb[67];
    __shared__ float red[128];
    int u = blockIdx.x, t = threadIdx.x;
    if (t < 2) comb[t] = uavs[u * 2 + t];
    else if (t < 66) comb[t] = emb[u * 64 + (t - 2)];
    else if (t == 66) comb[t] = speeds[u];
    __syncthreads();
    float a = bc1[t];
    for (int i = 0; i < 67; ++i) a = fmaf(comb[i], Wc1[i * 128 + t], a);
    a = fmaxf(a, 0.f);
    red[t] = a * Wc2[t];
    __syncthreads();
    for (int sft = 64; sft > 0; sft >>= 1) {
        if (t < sft) red[t] += red[t + sft];
        __syncthreads();
    }
    if (t == 0) {
        out[u]      = 1.0f;                 // softmax over singleton axis
        out[16 + u] = red[0] + bc2[0];
    }
}

extern "C" void kernel_launch(void* const* d_in, const int* in_sizes, int n_in,
                              void* d_out, int out_size, void* d_ws, size_t ws_size,
                              hipStream_t stream)
{
    const float* mission_coords = (const float*)d_in[0];
    const float* uavs_info      = (const float*)d_in[1];
    const float* speeds         = (const float*)d_in[2];
    const float* dist_matrix    = (const float*)d_in[3];
    const float* timetogo       = (const float*)d_in[4];
    const int*   action_mask    = (const int*)d_in[5];
    const int*   edge_index     = (const int*)d_in[6];
    const float* Wq0 = (const float*)d_in[8];  const float* bq0 = (const float*)d_in[9];
    const float* Wk0 = (const float*)d_in[10]; const float* bk0 = (const float*)d_in[11];
    const float* Wv0 = (const float*)d_in[12]; const float* bv0 = (const float*)d_in[13];
    const float* Ws0 = (const float*)d_in[14]; const float* bs0 = (const float*)d_in[15];
    const float* Wq  = (const float*)d_in[16]; const float* bq  = (const float*)d_in[17];
    const float* Wk  = (const float*)d_in[18]; const float* bk  = (const float*)d_in[19];
    const float* Wv  = (const float*)d_in[20]; const float* bv  = (const float*)d_in[21];
    const float* Ws  = (const float*)d_in[22]; const float* bs  = (const float*)d_in[23];
    const float* Wout = (const float*)d_in[24]; const float* bout = (const float*)d_in[25];
    const float* Wc1 = (const float*)d_in[30]; const float* bc1 = (const float*)d_in[31];
    const float* Wc2 = (const float*)d_in[32]; const float* bc2 = (const float*)d_in[33];
    float* out = (float*)d_out;

    const int* e_src = edge_index;
    const int* e_dst = edge_index + NEDGES;

    // ---- workspace carve ----
    char* p = (char*)d_ws;
    ushort* Ybf = (ushort*)p;  p += (size_t)NNODES * NQKVS * 2;   // 32 MB
    ushort* Xbf = (ushort*)p;  p += (size_t)NNODES * HID * 2;     // 8 MB
    ushort* Wt  = (ushort*)p;  p += (size_t)3 * NQKVS * HID * 2;  // 6 MB
    unsigned char* Kf8 = (unsigned char*)p; p += (size_t)NNODES * HID; // 4 MB
    float* bcat = (float*)p;   p += (size_t)3 * NQKVS * 4;
    float* x6   = (float*)p;   p += (size_t)NNODES * 6 * 4;
    float* xsumP = (float*)p;  p += (size_t)UU * 8 * HID * 4;
    float* emb  = (float*)p;   p += (size_t)UU * 64 * 4;
    int* cnt    = (int*)p;     p += (size_t)NNODES * 4;
    int* indptr = (int*)p;     p += (size_t)(NNODES + 1) * 4;
    int* cursor = (int*)p;     p += (size_t)NNODES * 4;
    int* ssrc   = (int*)p;     p += (size_t)NEDGES * 4;

    hipMemsetAsync(cnt, 0, NNODES * sizeof(int), stream);
    hipMemsetAsync(cursor, 0, NNODES * sizeof(int), stream);

    // ---- prep: features, weights, CSR ----
    k_build_x<<<NNODES / 256, 256, 0, stream>>>(mission_coords, speeds, dist_matrix,
                                                timetogo, action_mask, x6);
    k_wt<<<dim3(8, 8, 12), 256, 0, stream>>>(Wq, Wk, Wv, Ws, Wt);
    k_bias<<<3 * NQKVS / 256, 256, 0, stream>>>(bq, bk, bv, bs, bcat);
    k_hist<<<NEDGES / 256, 256, 0, stream>>>(e_dst, cnt);
    k_scan<<<1, 256, 0, stream>>>(cnt, indptr);
    k_scatter<<<NEDGES / 256, 256, 0, stream>>>(e_src, e_dst, indptr, cursor, ssrc);

    // ---- layer 0 (in=6) ----
    k_lin0<<<NNODES, 256, 0, stream>>>(x6, Wq0, bq0, Wk0, bk0, Wv0, bv0, Ws0, bs0, Ybf, Kf8);
    k_attn<<<NNODES / 4, 256, 0, stream>>>(indptr, ssrc, Ybf, Kf8, Xbf);

    // ---- layers 1..3: fused q|k|v|s MFMA GEMM + attention ----
    const int ngblocks = (NNODES / GBM) * (NQKVS / GBN);   // 1024
    for (int l = 0; l < 3; ++l) {
        k_gemm<<<ngblocks, 256, 0, stream>>>(Xbf, Wt + (size_t)l * NQKVS * HID,
                                             bcat + l * NQKVS, Ybf, Kf8);
        k_attn<<<NNODES / 4, 256, 0, stream>>>(indptr, ssrc, Ybf, Kf8, Xbf);
    }

    // ---- pooling + embedding + head ----
    k_pool<<<dim3(UU, 8), 512, 0, stream>>>(Xbf, xsumP);
    k_emb<<<UU, 512, 0, stream>>>(xsumP, Wout, bout, emb);
    k_head<<<UU, 128, 0, stream>>>(uavs_info, speeds, emb, Wc1, bc1, Wc2, bc2, out);
}